// Round 1
// baseline (438.779 us; speedup 1.0000x reference)
//
#include <hip/hip_runtime.h>
#include <hip/hip_bf16.h>

typedef __attribute__((ext_vector_type(8))) short short8;
typedef __attribute__((ext_vector_type(4))) float floatx4;

#define B_ 8
#define T_ 1024
#define S_ 1500
#define SP 1536
#define D_ 1024
#define H_ 16
#define DH 64
// q-scale with log2(e) folded in: exp(x) = exp2(x * log2e)
#define SCALE2_ 0.1803368801111244f

__device__ __forceinline__ unsigned short f2bf(float f) {
  unsigned u = __float_as_uint(f);
  u += 0x7fffu + ((u >> 16) & 1u);
  return (unsigned short)(u >> 16);
}

__device__ __forceinline__ floatx4 mfma16(short8 a, short8 b, floatx4 c) {
  return __builtin_amdgcn_mfma_f32_16x16x32_bf16(a, b, c, 0, 0, 0);
}

// async global->LDS, 16B per lane. LDS dest = wave-uniform base + lane*16.
__device__ __forceinline__ void gload_lds16(const unsigned short* g, unsigned short* l) {
  __builtin_amdgcn_global_load_lds(
      (const __attribute__((address_space(1))) unsigned int*)g,
      (__attribute__((address_space(3))) unsigned int*)(unsigned long)(uintptr_t)l, 16, 0, 0);
}

// ---------------- prep: fused fp32 -> bf16 cast for x, wq, wo ----------------
#define N1C (B_ * T_ * D_ / 4)
#define N2C (D_ * D_ / 4)
__global__ void cast3_kernel(const float* __restrict__ x, const float* __restrict__ wq,
                             const float* __restrict__ wo, unsigned short* __restrict__ xb,
                             unsigned short* __restrict__ wqb,
                             unsigned short* __restrict__ wob) {
  int i = blockIdx.x * blockDim.x + threadIdx.x;
  const float* src;
  unsigned short* dst;
  int j;
  if (i < N1C) {
    src = x; dst = xb; j = i;
  } else if (i < N1C + N2C) {
    src = wq; dst = wqb; j = i - N1C;
  } else {
    src = wo; dst = wob; j = i - N1C - N2C;
  }
  float4 v = ((const float4*)src)[j];
  ushort4 o;
  o.x = f2bf(v.x); o.y = f2bf(v.y); o.z = f2bf(v.z); o.w = f2bf(v.w);
  ((ushort4*)dst)[j] = o;
}

// ---------------- prep: K [B,S,H,DH] f32 -> [B,H,SP,DH] bf16, ROW-PERMUTED ------
__global__ void pack_k_kernel(const float* __restrict__ k,
                              unsigned short* __restrict__ kb) {
  int i = blockIdx.x * blockDim.x + threadIdx.x;  // group of 4 dh
  int dh4 = (i & 15) * 4;
  int j = i >> 4;
  int s = j % SP;   // staged position
  int bh = j / SP;
  if (bh >= B_ * H_) return;
  int b = bh >> 4, h = bh & 15;
  int p = s & 31;
  int src = (s & ~31) + ((p >> 2) & 3) * 8 + ((p >> 4) & 1) * 4 + (p & 3);
  ushort4 o;
  if (src < S_) {
    float4 v = *(const float4*)(k + (((size_t)(b * S_ + src) * H_ + h) * DH) + dh4);
    o.x = f2bf(v.x); o.y = f2bf(v.y); o.z = f2bf(v.z); o.w = f2bf(v.w);
  } else {
    o = make_ushort4(0, 0, 0, 0);
  }
  *(ushort4*)(kb + ((size_t)bh * SP + s) * DH + dh4) = o;
}

// ---------------- prep: V [B,S,H,DH] f32 -> transposed [B,H,DH,SP] bf16 (plain) -
__global__ void pack_vt_kernel(const float* __restrict__ v,
                               unsigned short* __restrict__ vt) {
  __shared__ unsigned short tile[64][72];  // [dh][s], padded
  int st = blockIdx.x, bh = blockIdx.y;
  int b = bh >> 4, h = bh & 15;
  int s0 = st * 64;
  int t = threadIdx.x;
  for (int i = t; i < 1024; i += 256) {
    int sl = i >> 4, dh4 = (i & 15) * 4;
    float4 val = make_float4(0.f, 0.f, 0.f, 0.f);
    if (s0 + sl < S_)
      val = *(const float4*)(v + ((size_t)((b * S_ + s0 + sl) * H_ + h)) * DH + dh4);
    tile[dh4 + 0][sl] = f2bf(val.x);
    tile[dh4 + 1][sl] = f2bf(val.y);
    tile[dh4 + 2][sl] = f2bf(val.z);
    tile[dh4 + 3][sl] = f2bf(val.w);
  }
  __syncthreads();
  for (int i = t; i < 1024; i += 256) {
    int d = i >> 4, s4 = (i & 15) * 4;
    ushort4 o;
    o.x = tile[d][s4]; o.y = tile[d][s4 + 1]; o.z = tile[d][s4 + 2]; o.w = tile[d][s4 + 3];
    *(ushort4*)(vt + ((size_t)bh * DH + d) * SP + s0 + s4) = o;
  }
}

// ---------------- bf16 GEMM  C[m,n] = sum_k A[m,k]*B[n,k]  (+bias epilogues) -----
// m97-style: global_load_lds width=16 staging into UNPADDED [128][32] tiles with
// XOR chunk swizzle. Physical 16B-chunk slot pc at row r holds global chunk
// pc ^ ((r>>1)&3); fragment ds_read_b128 then lands 2 lanes/bank (free, m136).
// epi=0: qs output bf16, (val+bias)*SCALE2 (log2e folded), permuted to [B,H,T,DH]
// epi=1: fp32 output, val+bias, row-major [M,1024]
#define BK 32
__global__ __launch_bounds__(256, 4) void gemm_bt(const unsigned short* __restrict__ A,
                                                  const unsigned short* __restrict__ Bm,
                                                  const float* __restrict__ bias,
                                                  void* __restrict__ outp, int epi) {
  __shared__ unsigned short As[128 * BK];
  __shared__ unsigned short Bs[128 * BK];
  const int K = 1024;
  int t = threadIdx.x;
  int m0 = blockIdx.y * 128, n0 = blockIdx.x * 128;
  int w = t >> 6, lane = t & 63, quad = lane >> 4, l16 = lane & 15;
  int mw = (w & 1) * 64, nw = (w >> 1) * 64;

  // staging lane roles: each wave stages 16 rows per instr (lane i -> row base+i/4,
  // chunk slot i%4 which must hold global chunk g = (i%4) ^ ((row>>1)&3)
  int rloc = lane >> 2, c = lane & 3;
  int g = c ^ (((w * 16 + rloc) >> 1) & 3);  // +64 rows doesn't change ((row>>1)&3)
  const unsigned short* pa0 = A + (size_t)(m0 + w * 16 + rloc) * K + g * 8;
  const unsigned short* pa1 = pa0 + (size_t)64 * K;
  const unsigned short* pb0 = Bm + (size_t)(n0 + w * 16 + rloc) * K + g * 8;
  const unsigned short* pb1 = pb0 + (size_t)64 * K;
  unsigned short* lA0 = &As[(w * 16) * BK];
  unsigned short* lA1 = &As[(64 + w * 16) * BK];
  unsigned short* lB0 = &Bs[(w * 16) * BK];
  unsigned short* lB1 = &Bs[(64 + w * 16) * BK];

  floatx4 acc[4][4];
#pragma unroll
  for (int i = 0; i < 4; i++)
#pragma unroll
    for (int j = 0; j < 4; j++) {
      floatx4 z = {0.f, 0.f, 0.f, 0.f};
      acc[i][j] = z;
    }

  // fragment read offsets (swizzled)
  int arow = mw + l16;  // + mi*16
  int brow = nw + l16;  // + ni*16

  for (int kt = 0; kt < K / BK; kt++) {
    __syncthreads();  // previous tile's reads complete
    gload_lds16(pa0 + kt * BK, lA0);
    gload_lds16(pa1 + kt * BK, lA1);
    gload_lds16(pb0 + kt * BK, lB0);
    gload_lds16(pb1 + kt * BK, lB1);
    __syncthreads();  // drains vmcnt -> staged data visible

    short8 af[4], bf[4];
#pragma unroll
    for (int mi = 0; mi < 4; mi++) {
      int r = arow + mi * 16;
      int pc = quad ^ ((r >> 1) & 3);
      af[mi] = *(const short8*)&As[r * BK + pc * 8];
    }
#pragma unroll
    for (int ni = 0; ni < 4; ni++) {
      int r = brow + ni * 16;
      int pc = quad ^ ((r >> 1) & 3);
      bf[ni] = *(const short8*)&Bs[r * BK + pc * 8];
    }
#pragma unroll
    for (int mi = 0; mi < 4; mi++)
#pragma unroll
      for (int ni = 0; ni < 4; ni++)
        acc[mi][ni] = mfma16(af[mi], bf[ni], acc[mi][ni]);
  }

#pragma unroll
  for (int mi = 0; mi < 4; mi++)
#pragma unroll
    for (int ni = 0; ni < 4; ni++) {
      int row = m0 + mw + mi * 16 + quad * 4;
      int col = n0 + nw + ni * 16 + l16;
      float bcol = bias[col];
#pragma unroll
      for (int r = 0; r < 4; r++) {
        float val = acc[mi][ni][r] + bcol;
        int rr = row + r;
        if (epi == 0) {
          int b = rr >> 10, tt = rr & 1023, h = col >> 6, dh = col & 63;
          ((unsigned short*)outp)[(((size_t)(b * 16 + h) * 1024) + tt) * 64 + dh] =
              f2bf(val * SCALE2_);
        } else {
          ((float*)outp)[(size_t)rr * 1024 + col] = val;
        }
      }
    }
}

// ---------------- fused flash attention, Sc^T scheme, 8-wave blocks ----------
// grid (T/128, B*H) remapped XCD-chunked; block 512 (8 waves); wave owns 16 t-cols.
// Scores computed transposed: C col = t (lane), row = staged s (quad*4+reg).
// K is NOT staged in LDS: each lane reads its MFMA A-fragment straight from
// global (kb already holds the staged-row-permuted layout), so the LDS pipe --
// which was the saturated resource (8 waves x full K+V tile re-read per s-tile,
// ~57% LDS-busy) -- carries only V, while K rides the otherwise-idle VMEM/L1/L2
// path. XCD-chunked remap keeps all 8 t-tiles of a bh on one XCD so the K
// stream stays L2-hot. V staging is one-tile-ahead reg-preloaded (T14-lite).
// Softmax in base-2 domain (log2e folded into q scale).
__global__ __launch_bounds__(512, 4) void attn_kernel(
    const unsigned short* __restrict__ qs, const unsigned short* __restrict__ kb,
    const unsigned short* __restrict__ vt, unsigned short* __restrict__ ob) {
  __shared__ unsigned short Vs[64 * 136];   // [dh][s] padded (plain order)
  // XCD-chunked remap: dispatch index p runs on XCD p%8; choosing bh = p&127
  // puts the 8 t-tiles of each bh on one XCD (p = bh, bh+128, ... same mod 8).
  int p = blockIdx.x + (blockIdx.y << 3);
  int ttile = p >> 7, bh = p & 127;
  int b = bh >> 4, h = bh & 15;
  int t = threadIdx.x, w = t >> 6, lane = t & 63, quad = lane >> 4, l16 = lane & 15;

  // Q as B-operand: n = t = l16, k(dh) = quad*8 + j
  const unsigned short* qp =
      qs + ((size_t)bh * T_ + ttile * 128 + w * 16 + l16) * DH + quad * 8;
  short8 qa0 = *(const short8*)(qp);
  short8 qa1 = *(const short8*)(qp + 32);

  const unsigned short* kbase = kb + (size_t)bh * SP * DH;
  const unsigned short* vbase = vt + (size_t)bh * DH * SP;

  // K A-fragment per-lane base: staged row l16 (+nb*16 +s0), dh chunk quad*8
  const unsigned short* kfp = kbase + (size_t)l16 * DH + quad * 8;

  // V staging roles: thread copies int4 chunks i = t and i = t+512 of the
  // 64x128 tile: d = i>>4, c = i&15
  int vd = t >> 4, vc = t & 15;
  const unsigned short* vsp0 = vbase + (size_t)vd * SP + vc * 8;
  const unsigned short* vsp1 = vbase + (size_t)(vd + 32) * SP + vc * 8;
  unsigned short* vl0 = &Vs[vd * 136 + vc * 8];
  unsigned short* vl1 = &Vs[(vd + 32) * 136 + vc * 8];

  floatx4 o[4];  // O^T acc: col=t(l16), row = db*16 + quad*4 + r (= dh)
#pragma unroll
  for (int i = 0; i < 4; i++) {
    floatx4 z = {0.f, 0.f, 0.f, 0.f};
    o[i] = z;
  }
  float mrow = -1e30f, lrow = 0.f;  // per-lane: this lane's t-row state (base-2)

  // T14-lite: preload V tile 0 into regs; loads for tile i+1 issue before
  // compute of tile i so HBM/L2 latency hides under QK+softmax+PV.
  int4 rv0 = *(const int4*)(vsp0);
  int4 rv1 = *(const int4*)(vsp1);

  for (int s0 = 0; s0 < SP; s0 += 128) {
    __syncthreads();  // previous tile's PV reads of Vs complete
    *(int4*)vl0 = rv0;  // compiler inserts vmcnt wait for rv
    *(int4*)vl1 = rv1;
    __syncthreads();  // staged V visible
    if (s0 + 128 < SP) {
      rv0 = *(const int4*)(vsp0 + s0 + 128);
      rv1 = *(const int4*)(vsp1 + s0 + 128);
    }

    // Sc^T: per lane 32 staged-s values of its own t-row; K frags from global
    floatx4 sc[8];
    const unsigned short* kt0 = kfp + (size_t)s0 * DH;
#pragma unroll
    for (int nb = 0; nb < 8; nb++) {
      short8 k0 = *(const short8*)(kt0 + nb * 16 * DH);
      short8 k1 = *(const short8*)(kt0 + nb * 16 * DH + 32);
      floatx4 a = {0.f, 0.f, 0.f, 0.f};
      a = mfma16(k0, qa0, a);
      a = mfma16(k1, qa1, a);
      sc[nb] = a;
    }
    if (s0 + 128 > S_) {  // mask padded actual-s (last tile only)
#pragma unroll
      for (int nb = 0; nb < 8; nb++)
#pragma unroll
        for (int r = 0; r < 4; r++) {
          int s_act = s0 + (nb >> 1) * 32 + quad * 8 + (nb & 1) * 4 + r;
          if (s_act >= S_) sc[nb][r] = -1e30f;
        }
    }

    // online softmax (base 2): in-lane over 32 + 2 shfl across quads
    float mx = -1e30f;
#pragma unroll
    for (int nb = 0; nb < 8; nb++) {
      float a0m = fmaxf(sc[nb][0], sc[nb][1]);
      float a1m = fmaxf(sc[nb][2], sc[nb][3]);
      mx = fmaxf(mx, fmaxf(a0m, a1m));
    }
    mx = fmaxf(mx, __shfl_xor(mx, 16));
    mx = fmaxf(mx, __shfl_xor(mx, 32));
    float mnew = fmaxf(mrow, mx);
    float alpha = exp2f(mrow - mnew);
    mrow = mnew;
    float rs = 0.f;
#pragma unroll
    for (int nb = 0; nb < 8; nb++) {
#pragma unroll
      for (int r = 0; r < 4; r++) {
        float p2 = exp2f(sc[nb][r] - mnew);
        sc[nb][r] = p2;
        rs += p2;
      }
    }
    rs += __shfl_xor(rs, 16);
    rs += __shfl_xor(rs, 32);
    lrow = lrow * alpha + rs;
#pragma unroll
    for (int db = 0; db < 4; db++) {
      o[db][0] *= alpha; o[db][1] *= alpha; o[db][2] *= alpha; o[db][3] *= alpha;
    }

    // PV: O^T[d][t] += V^T(A) * P(B).  chunk c covers staged s = c*32..c*32+31
#pragma unroll
    for (int c = 0; c < 4; c++) {
      union { short8 v; __hip_bfloat162 h[4]; } pk;
      pk.h[0] = __float22bfloat162_rn(make_float2(sc[2 * c][0], sc[2 * c][1]));
      pk.h[1] = __float22bfloat162_rn(make_float2(sc[2 * c][2], sc[2 * c][3]));
      pk.h[2] = __float22bfloat162_rn(make_float2(sc[2 * c + 1][0], sc[2 * c + 1][1]));
      pk.h[3] = __float22bfloat162_rn(make_float2(sc[2 * c + 1][2], sc[2 * c + 1][3]));
#pragma unroll
      for (int db = 0; db < 4; db++) {
        short8 vf = *(const short8*)&Vs[(db * 16 + l16) * 136 + c * 32 + quad * 8];
        o[db] = mfma16(vf, pk.v, o[db]);
      }
    }
  }

  float inv = 1.0f / lrow;
  int tg = ttile * 128 + w * 16 + l16;
#pragma unroll
  for (int db = 0; db < 4; db++) {
    int dh = db * 16 + quad * 4;
    union { ushort4 s4; __hip_bfloat162 h[2]; } st;
    st.h[0] = __float22bfloat162_rn(make_float2(o[db][0] * inv, o[db][1] * inv));
    st.h[1] = __float22bfloat162_rn(make_float2(o[db][2] * inv, o[db][3] * inv));
    *(ushort4*)(ob + ((size_t)(b * T_ + tg) * H_ + h) * DH + dh) = st.s4;
  }
}

extern "C" void kernel_launch(void* const* d_in, const int* in_sizes, int n_in,
                              void* d_out, int out_size, void* d_ws, size_t ws_size,
                              hipStream_t stream) {
  const float* x  = (const float*)d_in[0];
  const float* k  = (const float*)d_in[1];
  const float* v  = (const float*)d_in[2];
  const float* wq = (const float*)d_in[3];
  const float* bq = (const float*)d_in[4];
  const float* wo = (const float*)d_in[5];
  const float* bo = (const float*)d_in[6];
  float* out = (float*)d_out;

  char* ws = (char*)d_ws;
  unsigned short* xb  = (unsigned short*)(ws + 0);
  unsigned short* wqb = (unsigned short*)(ws + 16777216);
  unsigned short* wob = (unsigned short*)(ws + 18874368);
  unsigned short* kbp = (unsigned short*)(ws + 20971520);
  unsigned short* vtp = (unsigned short*)(ws + 46137344);
  unsigned short* qsp = (unsigned short*)(ws + 71303168);
  unsigned short* obp = (unsigned short*)(ws + 88080384);

  {
    int blocks = (N1C + 2 * N2C) / 256;
    cast3_kernel<<<blocks, 256, 0, stream>>>(x, wq, wo, xb, wqb, wob);
  }
  {
    int groups = B_ * H_ * SP * 16;
    pack_k_kernel<<<groups / 256, 256, 0, stream>>>(k, kbp);
    pack_vt_kernel<<<dim3(SP / 64, B_ * H_), 256, 0, stream>>>(v, vtp);
  }
  gemm_bt<<<dim3(D_ / 128, B_ * T_ / 128), 256, 0, stream>>>(xb, wqb, bq, qsp, 0);
  attn_kernel<<<dim3(T_ / 128, B_ * H_), 512, 0, stream>>>(qsp, kbp, vtp, obp);
  gemm_bt<<<dim3(D_ / 128, B_ * T_ / 128), 256, 0, stream>>>(obp, wob, bo, out, 1);
}

// Round 2
// 340.060 us; speedup vs baseline: 1.2903x; 1.2903x over previous
//
#include <hip/hip_runtime.h>
#include <hip/hip_bf16.h>

typedef __attribute__((ext_vector_type(8))) short short8;
typedef __attribute__((ext_vector_type(4))) float floatx4;

#define B_ 8
#define T_ 1024
#define S_ 1500
#define SP 1536
#define D_ 1024
#define H_ 16
#define DH 64
// q-scale with log2(e) folded in: exp(x) = exp2(x * log2e)
#define SCALE2_ 0.1803368801111244f

__device__ __forceinline__ unsigned short f2bf(float f) {
  unsigned u = __float_as_uint(f);
  u += 0x7fffu + ((u >> 16) & 1u);
  return (unsigned short)(u >> 16);
}

__device__ __forceinline__ floatx4 mfma16(short8 a, short8 b, floatx4 c) {
  return __builtin_amdgcn_mfma_f32_16x16x32_bf16(a, b, c, 0, 0, 0);
}

// async global->LDS, 16B per lane. LDS dest = wave-uniform base + lane*16.
__device__ __forceinline__ void gload_lds16(const unsigned short* g, unsigned short* l) {
  __builtin_amdgcn_global_load_lds(
      (const __attribute__((address_space(1))) unsigned int*)g,
      (__attribute__((address_space(3))) unsigned int*)(unsigned long)(uintptr_t)l, 16, 0, 0);
}

// ---------------- prep: fused fp32 -> bf16 cast for x, wq, wo ----------------
#define N1C (B_ * T_ * D_ / 4)
#define N2C (D_ * D_ / 4)
__global__ void cast3_kernel(const float* __restrict__ x, const float* __restrict__ wq,
                             const float* __restrict__ wo, unsigned short* __restrict__ xb,
                             unsigned short* __restrict__ wqb,
                             unsigned short* __restrict__ wob) {
  int i = blockIdx.x * blockDim.x + threadIdx.x;
  const float* src;
  unsigned short* dst;
  int j;
  if (i < N1C) {
    src = x; dst = xb; j = i;
  } else if (i < N1C + N2C) {
    src = wq; dst = wqb; j = i - N1C;
  } else {
    src = wo; dst = wob; j = i - N1C - N2C;
  }
  float4 v = ((const float4*)src)[j];
  ushort4 o;
  o.x = f2bf(v.x); o.y = f2bf(v.y); o.z = f2bf(v.z); o.w = f2bf(v.w);
  ((ushort4*)dst)[j] = o;
}

// ---------------- prep: K [B,S,H,DH] f32 -> [B,H,SP,DH] bf16, ROW-PERMUTED ------
__global__ void pack_k_kernel(const float* __restrict__ k,
                              unsigned short* __restrict__ kb) {
  int i = blockIdx.x * blockDim.x + threadIdx.x;  // group of 4 dh
  int dh4 = (i & 15) * 4;
  int j = i >> 4;
  int s = j % SP;   // staged position
  int bh = j / SP;
  if (bh >= B_ * H_) return;
  int b = bh >> 4, h = bh & 15;
  int p = s & 31;
  int src = (s & ~31) + ((p >> 2) & 3) * 8 + ((p >> 4) & 1) * 4 + (p & 3);
  ushort4 o;
  if (src < S_) {
    float4 v = *(const float4*)(k + (((size_t)(b * S_ + src) * H_ + h) * DH) + dh4);
    o.x = f2bf(v.x); o.y = f2bf(v.y); o.z = f2bf(v.z); o.w = f2bf(v.w);
  } else {
    o = make_ushort4(0, 0, 0, 0);
  }
  *(ushort4*)(kb + ((size_t)bh * SP + s) * DH + dh4) = o;
}

// ---------------- prep: V [B,S,H,DH] f32 -> transposed [B,H,DH,SP] bf16 (plain) -
__global__ void pack_vt_kernel(const float* __restrict__ v,
                               unsigned short* __restrict__ vt) {
  __shared__ unsigned short tile[64][72];  // [dh][s], padded
  int st = blockIdx.x, bh = blockIdx.y;
  int b = bh >> 4, h = bh & 15;
  int s0 = st * 64;
  int t = threadIdx.x;
  for (int i = t; i < 1024; i += 256) {
    int sl = i >> 4, dh4 = (i & 15) * 4;
    float4 val = make_float4(0.f, 0.f, 0.f, 0.f);
    if (s0 + sl < S_)
      val = *(const float4*)(v + ((size_t)((b * S_ + s0 + sl) * H_ + h)) * DH + dh4);
    tile[dh4 + 0][sl] = f2bf(val.x);
    tile[dh4 + 1][sl] = f2bf(val.y);
    tile[dh4 + 2][sl] = f2bf(val.z);
    tile[dh4 + 3][sl] = f2bf(val.w);
  }
  __syncthreads();
  for (int i = t; i < 1024; i += 256) {
    int d = i >> 4, s4 = (i & 15) * 4;
    ushort4 o;
    o.x = tile[d][s4]; o.y = tile[d][s4 + 1]; o.z = tile[d][s4 + 2]; o.w = tile[d][s4 + 3];
    *(ushort4*)(vt + ((size_t)bh * DH + d) * SP + s0 + s4) = o;
  }
}

// ---------------- bf16 GEMM  C[m,n] = sum_k A[m,k]*B[n,k]  (+bias epilogues) -----
// m97-style: global_load_lds width=16 staging into UNPADDED [128][32] tiles with
// XOR chunk swizzle. Physical 16B-chunk slot pc at row r holds global chunk
// pc ^ ((r>>1)&3); fragment ds_read_b128 then lands 2 lanes/bank (free, m136).
// epi=0: qs output bf16, (val+bias)*SCALE2 (log2e folded), permuted to [B,H,T,DH]
// epi=1: fp32 output, val+bias, row-major [M,1024]
#define BK 32
__global__ __launch_bounds__(256, 4) void gemm_bt(const unsigned short* __restrict__ A,
                                                  const unsigned short* __restrict__ Bm,
                                                  const float* __restrict__ bias,
                                                  void* __restrict__ outp, int epi) {
  __shared__ unsigned short As[128 * BK];
  __shared__ unsigned short Bs[128 * BK];
  const int K = 1024;
  int t = threadIdx.x;
  int m0 = blockIdx.y * 128, n0 = blockIdx.x * 128;
  int w = t >> 6, lane = t & 63, quad = lane >> 4, l16 = lane & 15;
  int mw = (w & 1) * 64, nw = (w >> 1) * 64;

  // staging lane roles: each wave stages 16 rows per instr (lane i -> row base+i/4,
  // chunk slot i%4 which must hold global chunk g = (i%4) ^ ((row>>1)&3)
  int rloc = lane >> 2, c = lane & 3;
  int g = c ^ (((w * 16 + rloc) >> 1) & 3);  // +64 rows doesn't change ((row>>1)&3)
  const unsigned short* pa0 = A + (size_t)(m0 + w * 16 + rloc) * K + g * 8;
  const unsigned short* pa1 = pa0 + (size_t)64 * K;
  const unsigned short* pb0 = Bm + (size_t)(n0 + w * 16 + rloc) * K + g * 8;
  const unsigned short* pb1 = pb0 + (size_t)64 * K;
  unsigned short* lA0 = &As[(w * 16) * BK];
  unsigned short* lA1 = &As[(64 + w * 16) * BK];
  unsigned short* lB0 = &Bs[(w * 16) * BK];
  unsigned short* lB1 = &Bs[(64 + w * 16) * BK];

  floatx4 acc[4][4];
#pragma unroll
  for (int i = 0; i < 4; i++)
#pragma unroll
    for (int j = 0; j < 4; j++) {
      floatx4 z = {0.f, 0.f, 0.f, 0.f};
      acc[i][j] = z;
    }

  // fragment read offsets (swizzled)
  int arow = mw + l16;  // + mi*16
  int brow = nw + l16;  // + ni*16

  for (int kt = 0; kt < K / BK; kt++) {
    __syncthreads();  // previous tile's reads complete
    gload_lds16(pa0 + kt * BK, lA0);
    gload_lds16(pa1 + kt * BK, lA1);
    gload_lds16(pb0 + kt * BK, lB0);
    gload_lds16(pb1 + kt * BK, lB1);
    __syncthreads();  // drains vmcnt -> staged data visible

    short8 af[4], bf[4];
#pragma unroll
    for (int mi = 0; mi < 4; mi++) {
      int r = arow + mi * 16;
      int pc = quad ^ ((r >> 1) & 3);
      af[mi] = *(const short8*)&As[r * BK + pc * 8];
    }
#pragma unroll
    for (int ni = 0; ni < 4; ni++) {
      int r = brow + ni * 16;
      int pc = quad ^ ((r >> 1) & 3);
      bf[ni] = *(const short8*)&Bs[r * BK + pc * 8];
    }
#pragma unroll
    for (int mi = 0; mi < 4; mi++)
#pragma unroll
      for (int ni = 0; ni < 4; ni++)
        acc[mi][ni] = mfma16(af[mi], bf[ni], acc[mi][ni]);
  }

#pragma unroll
  for (int mi = 0; mi < 4; mi++)
#pragma unroll
    for (int ni = 0; ni < 4; ni++) {
      int row = m0 + mw + mi * 16 + quad * 4;
      int col = n0 + nw + ni * 16 + l16;
      float bcol = bias[col];
#pragma unroll
      for (int r = 0; r < 4; r++) {
        float val = acc[mi][ni][r] + bcol;
        int rr = row + r;
        if (epi == 0) {
          int b = rr >> 10, tt = rr & 1023, h = col >> 6, dh = col & 63;
          ((unsigned short*)outp)[(((size_t)(b * 16 + h) * 1024) + tt) * 64 + dh] =
              f2bf(val * SCALE2_);
        } else {
          ((float*)outp)[(size_t)rr * 1024 + col] = val;
        }
      }
    }
}

// ---------------- fused flash attention, Sc^T scheme, 8-wave blocks ----------
// grid (T/256, B*H) remapped XCD-chunked; block 512 (8 waves); wave owns 32 t-cols
// (TWO 16-col Q fragments). Doubling t-ownership halves LDS fragment reads per
// unit work: each K frag and V frag read from LDS feeds TWO mfmas (one per
// t-group). KVBLK=64 keeps sc at 2x4 floatx4 so regs fit the 4-wave/SIMD cap.
// K and V staged to LDS (R1's direct-global K read was latency-bound: 222us),
// reg-preloaded one tile ahead (T14-lite): exactly 1 int4 of K + 1 of V per
// thread per tile. Scores transposed: C col = t (lane), row = staged s.
// K staged row-permuted so P fragments re-pack in-lane as PV B-operand.
// Softmax in base-2 domain (log2e folded into q scale).
__global__ __launch_bounds__(512, 4) void attn_kernel(
    const unsigned short* __restrict__ qs, const unsigned short* __restrict__ kb,
    const unsigned short* __restrict__ vt, unsigned short* __restrict__ ob) {
  __shared__ unsigned short Ks[64 * 72];   // [staged s][dh] padded
  __shared__ unsigned short Vs[64 * 72];   // [dh][s] padded (plain order)
  // XCD-chunked remap: linear dispatch id q runs on XCD q%8; bh = q&127 puts
  // the 4 t-tiles of each bh on one XCD (q = bh, bh+128, ... same mod 8).
  int q = blockIdx.x + (blockIdx.y << 2);
  int ttile = q >> 7, bh = q & 127;
  int b = bh >> 4, h = bh & 15;
  int t = threadIdx.x, w = t >> 6, lane = t & 63, quad = lane >> 4, l16 = lane & 15;

  // Q as B-operand: two t-groups at w*32 and w*32+16; n = l16, k(dh) = quad*8+j
  const unsigned short* qp =
      qs + ((size_t)bh * T_ + ttile * 256 + w * 32 + l16) * DH + quad * 8;
  short8 qa[2][2];
  qa[0][0] = *(const short8*)(qp);
  qa[0][1] = *(const short8*)(qp + 32);
  qa[1][0] = *(const short8*)(qp + 16 * DH);
  qa[1][1] = *(const short8*)(qp + 16 * DH + 32);

  const unsigned short* kbase = kb + (size_t)bh * SP * DH;
  const unsigned short* vbase = vt + (size_t)bh * DH * SP;

  // staging roles: thread owns one int4 of K and one of V per tile
  int sr = t >> 3, sc8 = (t & 7) * 8;
  const unsigned short* ksp = kbase + (size_t)sr * DH + sc8;
  const unsigned short* vsp = vbase + (size_t)sr * SP + sc8;
  unsigned short* kl = &Ks[sr * 72 + sc8];
  unsigned short* vl = &Vs[sr * 72 + sc8];

  floatx4 o[2][4];  // O^T acc per t-group: col=t(l16), row = db*16 + quad*4 + r
#pragma unroll
  for (int g = 0; g < 2; g++)
#pragma unroll
    for (int i = 0; i < 4; i++) {
      floatx4 z = {0.f, 0.f, 0.f, 0.f};
      o[g][i] = z;
    }
  float mrow[2] = {-1e30f, -1e30f};
  float lrow[2] = {0.f, 0.f};

  // T14-lite: preload tile 0; loads for tile i+1 issue before compute of tile i
  int4 rk = *(const int4*)(ksp);
  int4 rv = *(const int4*)(vsp);

  for (int s0 = 0; s0 < SP; s0 += 64) {
    __syncthreads();    // previous tile's LDS reads complete
    *(int4*)kl = rk;    // compiler inserts vmcnt wait
    *(int4*)vl = rv;
    __syncthreads();    // staged tile visible
    if (s0 + 64 < SP) {
      rk = *(const int4*)(ksp + (size_t)(s0 + 64) * DH);
      rv = *(const int4*)(vsp + s0 + 64);
    }

    // Sc^T: per lane, per t-group, 16 staged-s values of its own t-row.
    // Each K fragment read feeds BOTH t-groups' mfmas.
    floatx4 sc[2][4];
#pragma unroll
    for (int nb = 0; nb < 4; nb++) {
      short8 k0 = *(const short8*)&Ks[(nb * 16 + l16) * 72 + quad * 8];
      short8 k1 = *(const short8*)&Ks[(nb * 16 + l16) * 72 + 32 + quad * 8];
      floatx4 a = {0.f, 0.f, 0.f, 0.f};
      a = mfma16(k0, qa[0][0], a);
      a = mfma16(k1, qa[0][1], a);
      sc[0][nb] = a;
      floatx4 a2 = {0.f, 0.f, 0.f, 0.f};
      a2 = mfma16(k0, qa[1][0], a2);
      a2 = mfma16(k1, qa[1][1], a2);
      sc[1][nb] = a2;
    }
    if (s0 + 64 > S_) {  // mask padded actual-s (last tile only)
#pragma unroll
      for (int nb = 0; nb < 4; nb++)
#pragma unroll
        for (int r = 0; r < 4; r++) {
          int s_act = s0 + (nb >> 1) * 32 + quad * 8 + (nb & 1) * 4 + r;
          if (s_act >= S_) { sc[0][nb][r] = -1e30f; sc[1][nb][r] = -1e30f; }
        }
    }

    // online softmax (base 2) per t-group: in-lane over 16 + 2 shfl across quads
#pragma unroll
    for (int g = 0; g < 2; g++) {
      float mx = -1e30f;
#pragma unroll
      for (int nb = 0; nb < 4; nb++) {
        float a0m = fmaxf(sc[g][nb][0], sc[g][nb][1]);
        float a1m = fmaxf(sc[g][nb][2], sc[g][nb][3]);
        mx = fmaxf(mx, fmaxf(a0m, a1m));
      }
      mx = fmaxf(mx, __shfl_xor(mx, 16));
      mx = fmaxf(mx, __shfl_xor(mx, 32));
      float mnew = fmaxf(mrow[g], mx);
      float alpha = exp2f(mrow[g] - mnew);
      mrow[g] = mnew;
      float rs = 0.f;
#pragma unroll
      for (int nb = 0; nb < 4; nb++)
#pragma unroll
        for (int r = 0; r < 4; r++) {
          float p2 = exp2f(sc[g][nb][r] - mnew);
          sc[g][nb][r] = p2;
          rs += p2;
        }
      rs += __shfl_xor(rs, 16);
      rs += __shfl_xor(rs, 32);
      lrow[g] = lrow[g] * alpha + rs;
#pragma unroll
      for (int db = 0; db < 4; db++) {
        o[g][db][0] *= alpha; o[g][db][1] *= alpha;
        o[g][db][2] *= alpha; o[g][db][3] *= alpha;
      }
    }

    // PV: O^T[d][t] += V^T(A) * P(B). chunk c covers staged s = c*32..c*32+31.
    // Each V fragment read feeds BOTH t-groups' mfmas.
#pragma unroll
    for (int c = 0; c < 2; c++) {
      union { short8 v; __hip_bfloat162 h[4]; } pk0, pk1;
      pk0.h[0] = __float22bfloat162_rn(make_float2(sc[0][2 * c][0], sc[0][2 * c][1]));
      pk0.h[1] = __float22bfloat162_rn(make_float2(sc[0][2 * c][2], sc[0][2 * c][3]));
      pk0.h[2] = __float22bfloat162_rn(make_float2(sc[0][2 * c + 1][0], sc[0][2 * c + 1][1]));
      pk0.h[3] = __float22bfloat162_rn(make_float2(sc[0][2 * c + 1][2], sc[0][2 * c + 1][3]));
      pk1.h[0] = __float22bfloat162_rn(make_float2(sc[1][2 * c][0], sc[1][2 * c][1]));
      pk1.h[1] = __float22bfloat162_rn(make_float2(sc[1][2 * c][2], sc[1][2 * c][3]));
      pk1.h[2] = __float22bfloat162_rn(make_float2(sc[1][2 * c + 1][0], sc[1][2 * c + 1][1]));
      pk1.h[3] = __float22bfloat162_rn(make_float2(sc[1][2 * c + 1][2], sc[1][2 * c + 1][3]));
#pragma unroll
      for (int db = 0; db < 4; db++) {
        short8 vf = *(const short8*)&Vs[(db * 16 + l16) * 72 + c * 32 + quad * 8];
        o[0][db] = mfma16(vf, pk0.v, o[0][db]);
        o[1][db] = mfma16(vf, pk1.v, o[1][db]);
      }
    }
  }

#pragma unroll
  for (int g = 0; g < 2; g++) {
    float inv = 1.0f / lrow[g];
    int tg = ttile * 256 + w * 32 + g * 16 + l16;
#pragma unroll
    for (int db = 0; db < 4; db++) {
      int dh = db * 16 + quad * 4;
      union { ushort4 s4; __hip_bfloat162 h[2]; } st;
      st.h[0] = __float22bfloat162_rn(make_float2(o[g][db][0] * inv, o[g][db][1] * inv));
      st.h[1] = __float22bfloat162_rn(make_float2(o[g][db][2] * inv, o[g][db][3] * inv));
      *(ushort4*)(ob + ((size_t)(b * T_ + tg) * H_ + h) * DH + dh) = st.s4;
    }
  }
}

extern "C" void kernel_launch(void* const* d_in, const int* in_sizes, int n_in,
                              void* d_out, int out_size, void* d_ws, size_t ws_size,
                              hipStream_t stream) {
  const float* x  = (const float*)d_in[0];
  const float* k  = (const float*)d_in[1];
  const float* v  = (const float*)d_in[2];
  const float* wq = (const float*)d_in[3];
  const float* bq = (const float*)d_in[4];
  const float* wo = (const float*)d_in[5];
  const float* bo = (const float*)d_in[6];
  float* out = (float*)d_out;

  char* ws = (char*)d_ws;
  unsigned short* xb  = (unsigned short*)(ws + 0);
  unsigned short* wqb = (unsigned short*)(ws + 16777216);
  unsigned short* wob = (unsigned short*)(ws + 18874368);
  unsigned short* kbp = (unsigned short*)(ws + 20971520);
  unsigned short* vtp = (unsigned short*)(ws + 46137344);
  unsigned short* qsp = (unsigned short*)(ws + 71303168);
  unsigned short* obp = (unsigned short*)(ws + 88080384);

  {
    int blocks = (N1C + 2 * N2C) / 256;
    cast3_kernel<<<blocks, 256, 0, stream>>>(x, wq, wo, xb, wqb, wob);
  }
  {
    int groups = B_ * H_ * SP * 16;
    pack_k_kernel<<<groups / 256, 256, 0, stream>>>(k, kbp);
    pack_vt_kernel<<<dim3(SP / 64, B_ * H_), 256, 0, stream>>>(v, vtp);
  }
  gemm_bt<<<dim3(D_ / 128, B_ * T_ / 128), 256, 0, stream>>>(xb, wqb, bq, qsp, 0);
  attn_kernel<<<dim3(T_ / 256, B_ * H_), 512, 0, stream>>>(qsp, kbp, vtp, obp);
  gemm_bt<<<dim3(D_ / 128, B_ * T_ / 128), 256, 0, stream>>>(obp, wob, bo, out, 1);
}

// Round 4
// 328.168 us; speedup vs baseline: 1.3371x; 1.0362x over previous
//
#include <hip/hip_runtime.h>
#include <hip/hip_bf16.h>

typedef __attribute__((ext_vector_type(8))) short short8;
typedef __attribute__((ext_vector_type(4))) float floatx4;

#define B_ 8
#define T_ 1024
#define S_ 1500
#define SP 1536
#define D_ 1024
#define H_ 16
#define DH 64
// q-scale with log2(e) folded in: exp(x) = exp2(x * log2e)
#define SCALE2_ 0.1803368801111244f

__device__ __forceinline__ unsigned short f2bf(float f) {
  unsigned u = __float_as_uint(f);
  u += 0x7fffu + ((u >> 16) & 1u);
  return (unsigned short)(u >> 16);
}

__device__ __forceinline__ floatx4 mfma16(short8 a, short8 b, floatx4 c) {
  return __builtin_amdgcn_mfma_f32_16x16x32_bf16(a, b, c, 0, 0, 0);
}

// async global->LDS, 16B per lane. LDS dest = wave-uniform base + lane*16.
__device__ __forceinline__ void gload_lds16(const unsigned short* g, unsigned short* l) {
  __builtin_amdgcn_global_load_lds(
      (const __attribute__((address_space(1))) unsigned int*)g,
      (__attribute__((address_space(3))) unsigned int*)(unsigned long)(uintptr_t)l, 16, 0, 0);
}

// ---------------- prep: fused fp32 -> bf16 cast for x, wq, wo ----------------
#define N1C (B_ * T_ * D_ / 4)
#define N2C (D_ * D_ / 4)
__global__ void cast3_kernel(const float* __restrict__ x, const float* __restrict__ wq,
                             const float* __restrict__ wo, unsigned short* __restrict__ xb,
                             unsigned short* __restrict__ wqb,
                             unsigned short* __restrict__ wob) {
  int i = blockIdx.x * blockDim.x + threadIdx.x;
  const float* src;
  unsigned short* dst;
  int j;
  if (i < N1C) {
    src = x; dst = xb; j = i;
  } else if (i < N1C + N2C) {
    src = wq; dst = wqb; j = i - N1C;
  } else {
    src = wo; dst = wob; j = i - N1C - N2C;
  }
  float4 v = ((const float4*)src)[j];
  ushort4 o;
  o.x = f2bf(v.x); o.y = f2bf(v.y); o.z = f2bf(v.z); o.w = f2bf(v.w);
  ((ushort4*)dst)[j] = o;
}

// ---------------- prep: K [B,S,H,DH] f32 -> [B,H,SP,DH] bf16, ROW-PERMUTED ------
__global__ void pack_k_kernel(const float* __restrict__ k,
                              unsigned short* __restrict__ kb) {
  int i = blockIdx.x * blockDim.x + threadIdx.x;  // group of 4 dh
  int dh4 = (i & 15) * 4;
  int j = i >> 4;
  int s = j % SP;   // staged position
  int bh = j / SP;
  if (bh >= B_ * H_) return;
  int b = bh >> 4, h = bh & 15;
  int p = s & 31;
  int src = (s & ~31) + ((p >> 2) & 3) * 8 + ((p >> 4) & 1) * 4 + (p & 3);
  ushort4 o;
  if (src < S_) {
    float4 v = *(const float4*)(k + (((size_t)(b * S_ + src) * H_ + h) * DH) + dh4);
    o.x = f2bf(v.x); o.y = f2bf(v.y); o.z = f2bf(v.z); o.w = f2bf(v.w);
  } else {
    o = make_ushort4(0, 0, 0, 0);
  }
  *(ushort4*)(kb + ((size_t)bh * SP + s) * DH + dh4) = o;
}

// ---------------- prep: V [B,S,H,DH] f32 -> transposed [B,H,DH,SP] bf16 (plain) -
__global__ void pack_vt_kernel(const float* __restrict__ v,
                               unsigned short* __restrict__ vt) {
  __shared__ unsigned short tile[64][72];  // [dh][s], padded
  int st = blockIdx.x, bh = blockIdx.y;
  int b = bh >> 4, h = bh & 15;
  int s0 = st * 64;
  int t = threadIdx.x;
  for (int i = t; i < 1024; i += 256) {
    int sl = i >> 4, dh4 = (i & 15) * 4;
    float4 val = make_float4(0.f, 0.f, 0.f, 0.f);
    if (s0 + sl < S_)
      val = *(const float4*)(v + ((size_t)((b * S_ + s0 + sl) * H_ + h)) * DH + dh4);
    tile[dh4 + 0][sl] = f2bf(val.x);
    tile[dh4 + 1][sl] = f2bf(val.y);
    tile[dh4 + 2][sl] = f2bf(val.z);
    tile[dh4 + 3][sl] = f2bf(val.w);
  }
  __syncthreads();
  for (int i = t; i < 1024; i += 256) {
    int d = i >> 4, s4 = (i & 15) * 4;
    ushort4 o;
    o.x = tile[d][s4]; o.y = tile[d][s4 + 1]; o.z = tile[d][s4 + 2]; o.w = tile[d][s4 + 3];
    *(ushort4*)(vt + ((size_t)bh * DH + d) * SP + s0 + s4) = o;
  }
}

// ---------------- bf16 GEMM  C[m,n] = sum_k A[m,k]*B[n,k]  (+bias epilogues) -----
// m97-style: global_load_lds width=16 staging into UNPADDED [128][32] tiles with
// XOR chunk swizzle. Physical 16B-chunk slot pc at row r holds global chunk
// pc ^ ((r>>1)&3); fragment ds_read_b128 then lands 2 lanes/bank (free, m136).
// epi=0: qs output bf16, (val+bias)*SCALE2 (log2e folded), permuted to [B,H,T,DH]
// epi=1: fp32 output, val+bias, row-major [M,1024]
#define BK 32
__global__ __launch_bounds__(256, 4) void gemm_bt(const unsigned short* __restrict__ A,
                                                  const unsigned short* __restrict__ Bm,
                                                  const float* __restrict__ bias,
                                                  void* __restrict__ outp, int epi) {
  __shared__ unsigned short As[128 * BK];
  __shared__ unsigned short Bs[128 * BK];
  const int K = 1024;
  int t = threadIdx.x;
  int m0 = blockIdx.y * 128, n0 = blockIdx.x * 128;
  int w = t >> 6, lane = t & 63, quad = lane >> 4, l16 = lane & 15;
  int mw = (w & 1) * 64, nw = (w >> 1) * 64;

  // staging lane roles: each wave stages 16 rows per instr (lane i -> row base+i/4,
  // chunk slot i%4 which must hold global chunk g = (i%4) ^ ((row>>1)&3)
  int rloc = lane >> 2, c = lane & 3;
  int g = c ^ (((w * 16 + rloc) >> 1) & 3);  // +64 rows doesn't change ((row>>1)&3)
  const unsigned short* pa0 = A + (size_t)(m0 + w * 16 + rloc) * K + g * 8;
  const unsigned short* pa1 = pa0 + (size_t)64 * K;
  const unsigned short* pb0 = Bm + (size_t)(n0 + w * 16 + rloc) * K + g * 8;
  const unsigned short* pb1 = pb0 + (size_t)64 * K;
  unsigned short* lA0 = &As[(w * 16) * BK];
  unsigned short* lA1 = &As[(64 + w * 16) * BK];
  unsigned short* lB0 = &Bs[(w * 16) * BK];
  unsigned short* lB1 = &Bs[(64 + w * 16) * BK];

  floatx4 acc[4][4];
#pragma unroll
  for (int i = 0; i < 4; i++)
#pragma unroll
    for (int j = 0; j < 4; j++) {
      floatx4 z = {0.f, 0.f, 0.f, 0.f};
      acc[i][j] = z;
    }

  // fragment read offsets (swizzled)
  int arow = mw + l16;  // + mi*16
  int brow = nw + l16;  // + ni*16

  for (int kt = 0; kt < K / BK; kt++) {
    __syncthreads();  // previous tile's reads complete
    gload_lds16(pa0 + kt * BK, lA0);
    gload_lds16(pa1 + kt * BK, lA1);
    gload_lds16(pb0 + kt * BK, lB0);
    gload_lds16(pb1 + kt * BK, lB1);
    __syncthreads();  // drains vmcnt -> staged data visible

    short8 af[4], bf[4];
#pragma unroll
    for (int mi = 0; mi < 4; mi++) {
      int r = arow + mi * 16;
      int pc = quad ^ ((r >> 1) & 3);
      af[mi] = *(const short8*)&As[r * BK + pc * 8];
    }
#pragma unroll
    for (int ni = 0; ni < 4; ni++) {
      int r = brow + ni * 16;
      int pc = quad ^ ((r >> 1) & 3);
      bf[ni] = *(const short8*)&Bs[r * BK + pc * 8];
    }
#pragma unroll
    for (int mi = 0; mi < 4; mi++)
#pragma unroll
      for (int ni = 0; ni < 4; ni++)
        acc[mi][ni] = mfma16(af[mi], bf[ni], acc[mi][ni]);
  }

#pragma unroll
  for (int mi = 0; mi < 4; mi++)
#pragma unroll
    for (int ni = 0; ni < 4; ni++) {
      int row = m0 + mw + mi * 16 + quad * 4;
      int col = n0 + nw + ni * 16 + l16;
      float bcol = bias[col];
#pragma unroll
      for (int r = 0; r < 4; r++) {
        float val = acc[mi][ni][r] + bcol;
        int rr = row + r;
        if (epi == 0) {
          int b = rr >> 10, tt = rr & 1023, h = col >> 6, dh = col & 63;
          ((unsigned short*)outp)[(((size_t)(b * 16 + h) * 1024) + tt) * 64 + dh] =
              f2bf(val * SCALE2_);
        } else {
          ((float*)outp)[(size_t)rr * 1024 + col] = val;
        }
      }
    }
}

// ---------------- fused flash attention, Sc^T scheme, 4-wave blocks ----------
// R2 post-mortem: 2x different LDS-read loads gave identical 125us -> kernel is
// latency/serialization-bound, not pipe-bound. R3 attacks stalls:
//  * 4-wave blocks (256 thr), wave owns 32 t-cols -> 1024 blocks = 4 independent
//    barrier domains per CU (2x streams to overlap stalls), barrier scope halved.
//  * double-buffered K/V LDS (2x18KB): ONE barrier per 64-s tile (was 2); the
//    stage-write -> read dependency leaves the per-tile critical path.
//  * staging loads issued TWO tiles ahead (full compute phase of vmcnt slack).
//  * defer-max (T13, THR=8 base-2): skip alpha/rescale chain when max growth
//    small; P bounded by 2^8, fp32 accums -> safe.
// Scores transposed: C col = t (lane), row = staged s. K staged row-permuted so
// P fragments re-pack in-lane as PV B-operand. Softmax in base-2 domain.
#define NT (SP / 64)
__global__ __launch_bounds__(256, 4) void attn_kernel(
    const unsigned short* __restrict__ qs, const unsigned short* __restrict__ kb,
    const unsigned short* __restrict__ vt, unsigned short* __restrict__ ob) {
  __shared__ unsigned short Ks[2][64 * 72];   // [buf][staged s][dh] padded
  __shared__ unsigned short Vs[2][64 * 72];   // [buf][dh][s] padded (plain order)
  // XCD-chunked remap: linear id p runs on XCD p%8; bh = p&127 puts the 8
  // t-tiles of each bh on one XCD (p = bh, bh+128, ... same mod 8).
  int p = blockIdx.x + (blockIdx.y << 3);
  int ttile = p >> 7, bh = p & 127;
  int b = bh >> 4, h = bh & 15;
  int t = threadIdx.x, w = t >> 6, lane = t & 63, quad = lane >> 4, l16 = lane & 15;

  // Q as B-operand: two t-groups at w*32 and w*32+16; n = l16, k(dh) = quad*8+j
  const unsigned short* qp =
      qs + ((size_t)bh * T_ + ttile * 128 + w * 32 + l16) * DH + quad * 8;
  short8 qa[2][2];
  qa[0][0] = *(const short8*)(qp);
  qa[0][1] = *(const short8*)(qp + 32);
  qa[1][0] = *(const short8*)(qp + 16 * DH);
  qa[1][1] = *(const short8*)(qp + 16 * DH + 32);

  const unsigned short* kbase = kb + (size_t)bh * SP * DH;
  const unsigned short* vbase = vt + (size_t)bh * DH * SP;

  // staging roles: 256 threads, 1024 int4 per tile -> 4 int4/thread (2 K + 2 V)
  int sr = t >> 3, c8 = (t & 7) * 8;
  const unsigned short* ksp0 = kbase + (size_t)sr * DH + c8;
  const unsigned short* ksp1 = kbase + (size_t)(sr + 32) * DH + c8;
  const unsigned short* vsp0 = vbase + (size_t)sr * SP + c8;
  const unsigned short* vsp1 = vbase + (size_t)(sr + 32) * SP + c8;
  int klo0 = sr * 72 + c8, klo1 = (sr + 32) * 72 + c8;
  int vlo0 = sr * 72 + c8, vlo1 = (sr + 32) * 72 + c8;

  floatx4 o[2][4];  // O^T acc per t-group: col=t(l16), row = db*16 + quad*4 + r
#pragma unroll
  for (int g = 0; g < 2; g++)
#pragma unroll
    for (int i = 0; i < 4; i++) {
      floatx4 z = {0.f, 0.f, 0.f, 0.f};
      o[g][i] = z;
    }
  float mrow[2] = {-1e30f, -1e30f};
  float lrow[2] = {0.f, 0.f};

  // prologue: tile0 -> regs -> buf0; issue tile1 loads
  int4 rk0 = *(const int4*)(ksp0);
  int4 rk1 = *(const int4*)(ksp1);
  int4 rv0 = *(const int4*)(vsp0);
  int4 rv1 = *(const int4*)(vsp1);
  *(int4*)&Ks[0][klo0] = rk0;
  *(int4*)&Ks[0][klo1] = rk1;
  *(int4*)&Vs[0][vlo0] = rv0;
  *(int4*)&Vs[0][vlo1] = rv1;
  rk0 = *(const int4*)(ksp0 + (size_t)64 * DH);
  rk1 = *(const int4*)(ksp1 + (size_t)64 * DH);
  rv0 = *(const int4*)(vsp0 + 64);
  rv1 = *(const int4*)(vsp1 + 64);

  for (int n = 0; n < NT; n++) {
    int s0 = n * 64;
    int cur = n & 1;
    __syncthreads();  // buf[cur] writes visible; buf[cur^1] reads (tile n-1) done
    if (n + 1 < NT) {  // write tile n+1 (regs) into the other buffer
      *(int4*)&Ks[cur ^ 1][klo0] = rk0;
      *(int4*)&Ks[cur ^ 1][klo1] = rk1;
      *(int4*)&Vs[cur ^ 1][vlo0] = rv0;
      *(int4*)&Vs[cur ^ 1][vlo1] = rv1;
    }
    if (n + 2 < NT) {  // issue loads for tile n+2 (consumed next iteration)
      size_t so = (size_t)(s0 + 128);
      rk0 = *(const int4*)(ksp0 + so * DH);
      rk1 = *(const int4*)(ksp1 + so * DH);
      rv0 = *(const int4*)(vsp0 + so);
      rv1 = *(const int4*)(vsp1 + so);
    }

    // Sc^T: per lane, per t-group, 16 staged-s values of its own t-row.
    // Each K fragment read feeds BOTH t-groups' mfmas.
    floatx4 sc[2][4];
#pragma unroll
    for (int nb = 0; nb < 4; nb++) {
      short8 k0 = *(const short8*)&Ks[cur][(nb * 16 + l16) * 72 + quad * 8];
      short8 k1 = *(const short8*)&Ks[cur][(nb * 16 + l16) * 72 + 32 + quad * 8];
      floatx4 a = {0.f, 0.f, 0.f, 0.f};
      a = mfma16(k0, qa[0][0], a);
      a = mfma16(k1, qa[0][1], a);
      sc[0][nb] = a;
      floatx4 a2 = {0.f, 0.f, 0.f, 0.f};
      a2 = mfma16(k0, qa[1][0], a2);
      a2 = mfma16(k1, qa[1][1], a2);
      sc[1][nb] = a2;
    }
    if (s0 + 64 > S_) {  // mask padded actual-s (last tile only)
#pragma unroll
      for (int nb = 0; nb < 4; nb++)
#pragma unroll
        for (int r = 0; r < 4; r++) {
          int s_act = s0 + (nb >> 1) * 32 + quad * 8 + (nb & 1) * 4 + r;
          if (s_act >= S_) { sc[0][nb][r] = -1e30f; sc[1][nb][r] = -1e30f; }
        }
    }

    // online softmax (base 2) per t-group, defer-max: only rescale when the
    // tile max exceeds the running max by >8 (then P <= 2^8, fp32-safe)
#pragma unroll
    for (int g = 0; g < 2; g++) {
      float mx = -1e30f;
#pragma unroll
      for (int nb = 0; nb < 4; nb++) {
        float a0m = fmaxf(sc[g][nb][0], sc[g][nb][1]);
        float a1m = fmaxf(sc[g][nb][2], sc[g][nb][3]);
        mx = fmaxf(mx, fmaxf(a0m, a1m));
      }
      mx = fmaxf(mx, __shfl_xor(mx, 16));
      mx = fmaxf(mx, __shfl_xor(mx, 32));
      if (__any(mx > mrow[g] + 8.0f)) {
        float mnew = fmaxf(mrow[g], mx);
        float alpha = exp2f(mrow[g] - mnew);
        mrow[g] = mnew;
        lrow[g] *= alpha;
#pragma unroll
        for (int db = 0; db < 4; db++) {
          o[g][db][0] *= alpha; o[g][db][1] *= alpha;
          o[g][db][2] *= alpha; o[g][db][3] *= alpha;
        }
      }
      float m = mrow[g];
      float rs = 0.f;
#pragma unroll
      for (int nb = 0; nb < 4; nb++)
#pragma unroll
        for (int r = 0; r < 4; r++) {
          float p2 = exp2f(sc[g][nb][r] - m);
          sc[g][nb][r] = p2;
          rs += p2;
        }
      rs += __shfl_xor(rs, 16);
      rs += __shfl_xor(rs, 32);
      lrow[g] += rs;
    }

    // PV: O^T[d][t] += V^T(A) * P(B). chunk c covers staged s = c*32..c*32+31.
    // Each V fragment read feeds BOTH t-groups' mfmas.
#pragma unroll
    for (int c = 0; c < 2; c++) {
      union { short8 v; __hip_bfloat162 h[4]; } pk0, pk1;
      pk0.h[0] = __float22bfloat162_rn(make_float2(sc[0][2 * c][0], sc[0][2 * c][1]));
      pk0.h[1] = __float22bfloat162_rn(make_float2(sc[0][2 * c][2], sc[0][2 * c][3]));
      pk0.h[2] = __float22bfloat162_rn(make_float2(sc[0][2 * c + 1][0], sc[0][2 * c + 1][1]));
      pk0.h[3] = __float22bfloat162_rn(make_float2(sc[0][2 * c + 1][2], sc[0][2 * c + 1][3]));
      pk1.h[0] = __float22bfloat162_rn(make_float2(sc[1][2 * c][0], sc[1][2 * c][1]));
      pk1.h[1] = __float22bfloat162_rn(make_float2(sc[1][2 * c][2], sc[1][2 * c][3]));
      pk1.h[2] = __float22bfloat162_rn(make_float2(sc[1][2 * c + 1][0], sc[1][2 * c + 1][1]));
      pk1.h[3] = __float22bfloat162_rn(make_float2(sc[1][2 * c + 1][2], sc[1][2 * c + 1][3]));
#pragma unroll
      for (int db = 0; db < 4; db++) {
        short8 vf = *(const short8*)&Vs[cur][(db * 16 + l16) * 72 + c * 32 + quad * 8];
        o[0][db] = mfma16(vf, pk0.v, o[0][db]);
        o[1][db] = mfma16(vf, pk1.v, o[1][db]);
      }
    }
  }

#pragma unroll
  for (int g = 0; g < 2; g++) {
    float inv = 1.0f / lrow[g];
    int tg = ttile * 128 + w * 32 + g * 16 + l16;
#pragma unroll
    for (int db = 0; db < 4; db++) {
      int dh = db * 16 + quad * 4;
      union { ushort4 s4; __hip_bfloat162 h[2]; } st;
      st.h[0] = __float22bfloat162_rn(make_float2(o[g][db][0] * inv, o[g][db][1] * inv));
      st.h[1] = __float22bfloat162_rn(make_float2(o[g][db][2] * inv, o[g][db][3] * inv));
      *(ushort4*)(ob + ((size_t)(b * T_ + tg) * H_ + h) * DH + dh) = st.s4;
    }
  }
}

extern "C" void kernel_launch(void* const* d_in, const int* in_sizes, int n_in,
                              void* d_out, int out_size, void* d_ws, size_t ws_size,
                              hipStream_t stream) {
  const float* x  = (const float*)d_in[0];
  const float* k  = (const float*)d_in[1];
  const float* v  = (const float*)d_in[2];
  const float* wq = (const float*)d_in[3];
  const float* bq = (const float*)d_in[4];
  const float* wo = (const float*)d_in[5];
  const float* bo = (const float*)d_in[6];
  float* out = (float*)d_out;

  char* ws = (char*)d_ws;
  unsigned short* xb  = (unsigned short*)(ws + 0);
  unsigned short* wqb = (unsigned short*)(ws + 16777216);
  unsigned short* wob = (unsigned short*)(ws + 18874368);
  unsigned short* kbp = (unsigned short*)(ws + 20971520);
  unsigned short* vtp = (unsigned short*)(ws + 46137344);
  unsigned short* qsp = (unsigned short*)(ws + 71303168);
  unsigned short* obp = (unsigned short*)(ws + 88080384);

  {
    int blocks = (N1C + 2 * N2C) / 256;
    cast3_kernel<<<blocks, 256, 0, stream>>>(x, wq, wo, xb, wqb, wob);
  }
  {
    int groups = B_ * H_ * SP * 16;
    pack_k_kernel<<<groups / 256, 256, 0, stream>>>(k, kbp);
    pack_vt_kernel<<<dim3(SP / 64, B_ * H_), 256, 0, stream>>>(v, vtp);
  }
  gemm_bt<<<dim3(D_ / 128, B_ * T_ / 128), 256, 0, stream>>>(xb, wqb, bq, qsp, 0);
  attn_kernel<<<dim3(T_ / 128, B_ * H_), 256, 0, stream>>>(qsp, kbp, vtp, obp);
  gemm_bt<<<dim3(D_ / 128, B_ * T_ / 128), 256, 0, stream>>>(obp, wob, bo, out, 1);
}

// Round 5
// 314.214 us; speedup vs baseline: 1.3964x; 1.0444x over previous
//
#include <hip/hip_runtime.h>
#include <hip/hip_bf16.h>

typedef __attribute__((ext_vector_type(8))) short short8;
typedef __attribute__((ext_vector_type(4))) float floatx4;

#define B_ 8
#define T_ 1024
#define S_ 1500
#define SP 1536
#define D_ 1024
#define H_ 16
#define DH 64
// q-scale with log2(e) folded in: exp(x) = exp2(x * log2e)
#define SCALE2_ 0.1803368801111244f

__device__ __forceinline__ unsigned short f2bf(float f) {
  unsigned u = __float_as_uint(f);
  u += 0x7fffu + ((u >> 16) & 1u);
  return (unsigned short)(u >> 16);
}

__device__ __forceinline__ floatx4 mfma16(short8 a, short8 b, floatx4 c) {
  return __builtin_amdgcn_mfma_f32_16x16x32_bf16(a, b, c, 0, 0, 0);
}

// async global->LDS, 16B per lane. LDS dest = wave-uniform base + lane*16.
__device__ __forceinline__ void gload_lds16(const unsigned short* g, unsigned short* l) {
  __builtin_amdgcn_global_load_lds(
      (const __attribute__((address_space(1))) unsigned int*)g,
      (__attribute__((address_space(3))) unsigned int*)(unsigned long)(uintptr_t)l, 16, 0, 0);
}

// ---------------- fused prep: cast3 + pack_k + pack_vt in ONE kernel ---------
// block-range dispatch: [0,10240) cast3, [10240,22528) pack_k, [22528,25600) pack_vt
#define N1C (B_ * T_ * D_ / 4)
#define N2C (D_ * D_ / 4)
#define NB_CAST ((N1C + 2 * N2C) / 256)          // 10240
#define NB_PK (B_ * H_ * SP * 16 / 256)          // 12288
#define NB_PVT ((SP / 64) * B_ * H_)             // 3072
__global__ void prep_kernel(const float* __restrict__ x, const float* __restrict__ k,
                            const float* __restrict__ v, const float* __restrict__ wq,
                            const float* __restrict__ wo,
                            unsigned short* __restrict__ xb,
                            unsigned short* __restrict__ wqb,
                            unsigned short* __restrict__ wob,
                            unsigned short* __restrict__ kb,
                            unsigned short* __restrict__ vt) {
  __shared__ unsigned short tile[64][72];  // pack_vt only
  int bid = blockIdx.x;
  int t = threadIdx.x;
  if (bid < NB_CAST) {
    // ---- fused fp32 -> bf16 cast for x, wq, wo ----
    int i = bid * 256 + t;
    const float* src;
    unsigned short* dst;
    int j;
    if (i < N1C) {
      src = x; dst = xb; j = i;
    } else if (i < N1C + N2C) {
      src = wq; dst = wqb; j = i - N1C;
    } else {
      src = wo; dst = wob; j = i - N1C - N2C;
    }
    float4 val = ((const float4*)src)[j];
    ushort4 o;
    o.x = f2bf(val.x); o.y = f2bf(val.y); o.z = f2bf(val.z); o.w = f2bf(val.w);
    ((ushort4*)dst)[j] = o;
  } else if (bid < NB_CAST + NB_PK) {
    // ---- K [B,S,H,DH] f32 -> [B,H,SP,DH] bf16, ROW-PERMUTED ----
    int i = (bid - NB_CAST) * 256 + t;  // group of 4 dh
    int dh4 = (i & 15) * 4;
    int j = i >> 4;
    int s = j % SP;   // staged position
    int bh = j / SP;
    if (bh < B_ * H_) {
      int b = bh >> 4, h = bh & 15;
      int p = s & 31;
      int src = (s & ~31) + ((p >> 2) & 3) * 8 + ((p >> 4) & 1) * 4 + (p & 3);
      ushort4 o;
      if (src < S_) {
        float4 val = *(const float4*)(k + (((size_t)(b * S_ + src) * H_ + h) * DH) + dh4);
        o.x = f2bf(val.x); o.y = f2bf(val.y); o.z = f2bf(val.z); o.w = f2bf(val.w);
      } else {
        o = make_ushort4(0, 0, 0, 0);
      }
      *(ushort4*)(kb + ((size_t)bh * SP + s) * DH + dh4) = o;
    }
  } else {
    // ---- V [B,S,H,DH] f32 -> transposed [B,H,DH,SP] bf16 (plain order) ----
    int q = bid - NB_CAST - NB_PK;
    int st = q % (SP / 64), bh = q / (SP / 64);
    int b = bh >> 4, h = bh & 15;
    int s0 = st * 64;
    for (int i = t; i < 1024; i += 256) {
      int sl = i >> 4, dh4 = (i & 15) * 4;
      float4 val = make_float4(0.f, 0.f, 0.f, 0.f);
      if (s0 + sl < S_)
        val = *(const float4*)(v + ((size_t)((b * S_ + s0 + sl) * H_ + h)) * DH + dh4);
      tile[dh4 + 0][sl] = f2bf(val.x);
      tile[dh4 + 1][sl] = f2bf(val.y);
      tile[dh4 + 2][sl] = f2bf(val.z);
      tile[dh4 + 3][sl] = f2bf(val.w);
    }
    __syncthreads();
    for (int i = t; i < 1024; i += 256) {
      int d = i >> 4, s4 = (i & 15) * 4;
      ushort4 o;
      o.x = tile[d][s4]; o.y = tile[d][s4 + 1]; o.z = tile[d][s4 + 2]; o.w = tile[d][s4 + 3];
      *(ushort4*)(vt + ((size_t)bh * DH + d) * SP + s0 + s4) = o;
    }
  }
}

// ---------------- bf16 GEMM  C[m,n] = sum_k A[m,k]*B[n,k]  (+bias epilogues) -----
// R5: BK 32->64 at constant 128^2 tile. K=1024 made the old loop barrier-drain
// bound (32 iters x 2 drains; only 16 MFMA/iter against ~500cy drain). BK=64
// halves the iterations/drains and doubles MFMA per iter. LDS 32KB -> still
// 4 blocks/CU. XOR swizzle: physical 16B-slot c at row r holds global chunk
// c ^ (r&7); fragment ds_read_b128 lands 2 lanes/bank (free, m136). Fragments
// read per-k-half to keep VGPR under the 128 cap (4 waves/EU).
// epi=0: qs output bf16, (val+bias)*SCALE2 (log2e folded), permuted to [B,H,T,DH]
// epi=1: fp32 output, val+bias, row-major [M,1024]
#define BK2 64
__global__ __launch_bounds__(256, 4) void gemm_bt(const unsigned short* __restrict__ A,
                                                  const unsigned short* __restrict__ Bm,
                                                  const float* __restrict__ bias,
                                                  void* __restrict__ outp, int epi) {
  __shared__ unsigned short As[128 * BK2];
  __shared__ unsigned short Bs[128 * BK2];
  const int K = 1024;
  int t = threadIdx.x;
  int m0 = blockIdx.y * 128, n0 = blockIdx.x * 128;
  int w = t >> 6, lane = t & 63, quad = lane >> 4, l16 = lane & 15;
  int mw = (w & 1) * 64, nw = (w >> 1) * 64;

  // staging: per wave-instr 8 rows x 8 slots; lane -> (rloc = lane>>3, c = lane&7).
  // slot c at row r must hold global chunk c ^ (r&7); staged row bases are
  // 8-aligned so r&7 == rloc.
  int rloc = lane >> 3, cslot = lane & 7;
  int gch = cslot ^ rloc;
  const unsigned short* paw = A + (size_t)(m0 + w * 8 + rloc) * K + gch * 8;
  const unsigned short* pbw = Bm + (size_t)(n0 + w * 8 + rloc) * K + gch * 8;
  unsigned short* lA = &As[(w * 8) * BK2];
  unsigned short* lB = &Bs[(w * 8) * BK2];

  floatx4 acc[4][4];
#pragma unroll
  for (int i = 0; i < 4; i++)
#pragma unroll
    for (int j = 0; j < 4; j++) {
      floatx4 z = {0.f, 0.f, 0.f, 0.f};
      acc[i][j] = z;
    }

  int arow = mw + l16;  // + mi*16
  int brow = nw + l16;  // + ni*16
  int sl7 = l16 & 7;    // r&7 for all fragment rows (16-multiples preserve it)

  for (int kt = 0; kt < K / BK2; kt++) {
    __syncthreads();  // previous tile's reads complete
#pragma unroll
    for (int p2 = 0; p2 < 4; p2++) {
      gload_lds16(paw + (size_t)(p2 * 32) * K + kt * BK2, lA + p2 * 32 * BK2);
      gload_lds16(pbw + (size_t)(p2 * 32) * K + kt * BK2, lB + p2 * 32 * BK2);
    }
    __syncthreads();  // drains vmcnt -> staged data visible

#pragma unroll
    for (int hf = 0; hf < 2; hf++) {
      int slot = ((hf << 2) | quad) ^ sl7;
      short8 af[4], bf[4];
#pragma unroll
      for (int mi = 0; mi < 4; mi++)
        af[mi] = *(const short8*)&As[(arow + mi * 16) * BK2 + slot * 8];
#pragma unroll
      for (int ni = 0; ni < 4; ni++)
        bf[ni] = *(const short8*)&Bs[(brow + ni * 16) * BK2 + slot * 8];
#pragma unroll
      for (int mi = 0; mi < 4; mi++)
#pragma unroll
        for (int ni = 0; ni < 4; ni++)
          acc[mi][ni] = mfma16(af[mi], bf[ni], acc[mi][ni]);
    }
  }

#pragma unroll
  for (int mi = 0; mi < 4; mi++)
#pragma unroll
    for (int ni = 0; ni < 4; ni++) {
      int row = m0 + mw + mi * 16 + quad * 4;
      int col = n0 + nw + ni * 16 + l16;
      float bcol = bias[col];
#pragma unroll
      for (int r = 0; r < 4; r++) {
        float val = acc[mi][ni][r] + bcol;
        int rr = row + r;
        if (epi == 0) {
          int b = rr >> 10, tt = rr & 1023, h = col >> 6, dh = col & 63;
          ((unsigned short*)outp)[(((size_t)(b * 16 + h) * 1024) + tt) * 64 + dh] =
              f2bf(val * SCALE2_);
        } else {
          ((float*)outp)[(size_t)rr * 1024 + col] = val;
        }
      }
    }
}

// ---------------- fused flash attention, Sc^T scheme, 4-wave blocks ----------
// (unchanged from R4: 125 -> 104us, prediction-validated structure)
//  * 4-wave blocks, wave owns 32 t-cols; 1024 blocks = 4 barrier domains/CU.
//  * double-buffered K/V LDS: ONE barrier per 64-s tile.
//  * staging loads issued TWO tiles ahead.
//  * defer-max (T13, THR=8 base-2).
// Scores transposed: C col = t (lane), row = staged s. K staged row-permuted so
// P fragments re-pack in-lane as PV B-operand. Softmax in base-2 domain.
#define NT (SP / 64)
__global__ __launch_bounds__(256, 4) void attn_kernel(
    const unsigned short* __restrict__ qs, const unsigned short* __restrict__ kb,
    const unsigned short* __restrict__ vt, unsigned short* __restrict__ ob) {
  __shared__ unsigned short Ks[2][64 * 72];   // [buf][staged s][dh] padded
  __shared__ unsigned short Vs[2][64 * 72];   // [buf][dh][s] padded (plain order)
  // XCD-chunked remap: linear id p runs on XCD p%8; bh = p&127 puts the 8
  // t-tiles of each bh on one XCD (p = bh, bh+128, ... same mod 8).
  int p = blockIdx.x + (blockIdx.y << 3);
  int ttile = p >> 7, bh = p & 127;
  int b = bh >> 4, h = bh & 15;
  int t = threadIdx.x, w = t >> 6, lane = t & 63, quad = lane >> 4, l16 = lane & 15;

  // Q as B-operand: two t-groups at w*32 and w*32+16; n = l16, k(dh) = quad*8+j
  const unsigned short* qp =
      qs + ((size_t)bh * T_ + ttile * 128 + w * 32 + l16) * DH + quad * 8;
  short8 qa[2][2];
  qa[0][0] = *(const short8*)(qp);
  qa[0][1] = *(const short8*)(qp + 32);
  qa[1][0] = *(const short8*)(qp + 16 * DH);
  qa[1][1] = *(const short8*)(qp + 16 * DH + 32);

  const unsigned short* kbase = kb + (size_t)bh * SP * DH;
  const unsigned short* vbase = vt + (size_t)bh * DH * SP;

  // staging roles: 256 threads, 1024 int4 per tile -> 4 int4/thread (2 K + 2 V)
  int sr = t >> 3, c8 = (t & 7) * 8;
  const unsigned short* ksp0 = kbase + (size_t)sr * DH + c8;
  const unsigned short* ksp1 = kbase + (size_t)(sr + 32) * DH + c8;
  const unsigned short* vsp0 = vbase + (size_t)sr * SP + c8;
  const unsigned short* vsp1 = vbase + (size_t)(sr + 32) * SP + c8;
  int klo0 = sr * 72 + c8, klo1 = (sr + 32) * 72 + c8;
  int vlo0 = sr * 72 + c8, vlo1 = (sr + 32) * 72 + c8;

  floatx4 o[2][4];  // O^T acc per t-group: col=t(l16), row = db*16 + quad*4 + r
#pragma unroll
  for (int g = 0; g < 2; g++)
#pragma unroll
    for (int i = 0; i < 4; i++) {
      floatx4 z = {0.f, 0.f, 0.f, 0.f};
      o[g][i] = z;
    }
  float mrow[2] = {-1e30f, -1e30f};
  float lrow[2] = {0.f, 0.f};

  // prologue: tile0 -> regs -> buf0; issue tile1 loads
  int4 rk0 = *(const int4*)(ksp0);
  int4 rk1 = *(const int4*)(ksp1);
  int4 rv0 = *(const int4*)(vsp0);
  int4 rv1 = *(const int4*)(vsp1);
  *(int4*)&Ks[0][klo0] = rk0;
  *(int4*)&Ks[0][klo1] = rk1;
  *(int4*)&Vs[0][vlo0] = rv0;
  *(int4*)&Vs[0][vlo1] = rv1;
  rk0 = *(const int4*)(ksp0 + (size_t)64 * DH);
  rk1 = *(const int4*)(ksp1 + (size_t)64 * DH);
  rv0 = *(const int4*)(vsp0 + 64);
  rv1 = *(const int4*)(vsp1 + 64);

  for (int n = 0; n < NT; n++) {
    int s0 = n * 64;
    int cur = n & 1;
    __syncthreads();  // buf[cur] writes visible; buf[cur^1] reads (tile n-1) done
    if (n + 1 < NT) {  // write tile n+1 (regs) into the other buffer
      *(int4*)&Ks[cur ^ 1][klo0] = rk0;
      *(int4*)&Ks[cur ^ 1][klo1] = rk1;
      *(int4*)&Vs[cur ^ 1][vlo0] = rv0;
      *(int4*)&Vs[cur ^ 1][vlo1] = rv1;
    }
    if (n + 2 < NT) {  // issue loads for tile n+2 (consumed next iteration)
      size_t so = (size_t)(s0 + 128);
      rk0 = *(const int4*)(ksp0 + so * DH);
      rk1 = *(const int4*)(ksp1 + so * DH);
      rv0 = *(const int4*)(vsp0 + so);
      rv1 = *(const int4*)(vsp1 + so);
    }

    // Sc^T: per lane, per t-group, 16 staged-s values of its own t-row.
    // Each K fragment read feeds BOTH t-groups' mfmas.
    floatx4 sc[2][4];
#pragma unroll
    for (int nb = 0; nb < 4; nb++) {
      short8 k0 = *(const short8*)&Ks[cur][(nb * 16 + l16) * 72 + quad * 8];
      short8 k1 = *(const short8*)&Ks[cur][(nb * 16 + l16) * 72 + 32 + quad * 8];
      floatx4 a = {0.f, 0.f, 0.f, 0.f};
      a = mfma16(k0, qa[0][0], a);
      a = mfma16(k1, qa[0][1], a);
      sc[0][nb] = a;
      floatx4 a2 = {0.f, 0.f, 0.f, 0.f};
      a2 = mfma16(k0, qa[1][0], a2);
      a2 = mfma16(k1, qa[1][1], a2);
      sc[1][nb] = a2;
    }
    if (s0 + 64 > S_) {  // mask padded actual-s (last tile only)
#pragma unroll
      for (int nb = 0; nb < 4; nb++)
#pragma unroll
        for (int r = 0; r < 4; r++) {
          int s_act = s0 + (nb >> 1) * 32 + quad * 8 + (nb & 1) * 4 + r;
          if (s_act >= S_) { sc[0][nb][r] = -1e30f; sc[1][nb][r] = -1e30f; }
        }
    }

    // online softmax (base 2) per t-group, defer-max: only rescale when the
    // tile max exceeds the running max by >8 (then P <= 2^8, fp32-safe)
#pragma unroll
    for (int g = 0; g < 2; g++) {
      float mx = -1e30f;
#pragma unroll
      for (int nb = 0; nb < 4; nb++) {
        float a0m = fmaxf(sc[g][nb][0], sc[g][nb][1]);
        float a1m = fmaxf(sc[g][nb][2], sc[g][nb][3]);
        mx = fmaxf(mx, fmaxf(a0m, a1m));
      }
      mx = fmaxf(mx, __shfl_xor(mx, 16));
      mx = fmaxf(mx, __shfl_xor(mx, 32));
      if (__any(mx > mrow[g] + 8.0f)) {
        float mnew = fmaxf(mrow[g], mx);
        float alpha = exp2f(mrow[g] - mnew);
        mrow[g] = mnew;
        lrow[g] *= alpha;
#pragma unroll
        for (int db = 0; db < 4; db++) {
          o[g][db][0] *= alpha; o[g][db][1] *= alpha;
          o[g][db][2] *= alpha; o[g][db][3] *= alpha;
        }
      }
      float m = mrow[g];
      float rs = 0.f;
#pragma unroll
      for (int nb = 0; nb < 4; nb++)
#pragma unroll
        for (int r = 0; r < 4; r++) {
          float p2 = exp2f(sc[g][nb][r] - m);
          sc[g][nb][r] = p2;
          rs += p2;
        }
      rs += __shfl_xor(rs, 16);
      rs += __shfl_xor(rs, 32);
      lrow[g] += rs;
    }

    // PV: O^T[d][t] += V^T(A) * P(B). chunk c covers staged s = c*32..c*32+31.
    // Each V fragment read feeds BOTH t-groups' mfmas.
#pragma unroll
    for (int c = 0; c < 2; c++) {
      union { short8 v; __hip_bfloat162 h[4]; } pk0, pk1;
      pk0.h[0] = __float22bfloat162_rn(make_float2(sc[0][2 * c][0], sc[0][2 * c][1]));
      pk0.h[1] = __float22bfloat162_rn(make_float2(sc[0][2 * c][2], sc[0][2 * c][3]));
      pk0.h[2] = __float22bfloat162_rn(make_float2(sc[0][2 * c + 1][0], sc[0][2 * c + 1][1]));
      pk0.h[3] = __float22bfloat162_rn(make_float2(sc[0][2 * c + 1][2], sc[0][2 * c + 1][3]));
      pk1.h[0] = __float22bfloat162_rn(make_float2(sc[1][2 * c][0], sc[1][2 * c][1]));
      pk1.h[1] = __float22bfloat162_rn(make_float2(sc[1][2 * c][2], sc[1][2 * c][3]));
      pk1.h[2] = __float22bfloat162_rn(make_float2(sc[1][2 * c + 1][0], sc[1][2 * c + 1][1]));
      pk1.h[3] = __float22bfloat162_rn(make_float2(sc[1][2 * c + 1][2], sc[1][2 * c + 1][3]));
#pragma unroll
      for (int db = 0; db < 4; db++) {
        short8 vf = *(const short8*)&Vs[cur][(db * 16 + l16) * 72 + c * 32 + quad * 8];
        o[0][db] = mfma16(vf, pk0.v, o[0][db]);
        o[1][db] = mfma16(vf, pk1.v, o[1][db]);
      }
    }
  }

#pragma unroll
  for (int g = 0; g < 2; g++) {
    float inv = 1.0f / lrow[g];
    int tg = ttile * 128 + w * 32 + g * 16 + l16;
#pragma unroll
    for (int db = 0; db < 4; db++) {
      int dh = db * 16 + quad * 4;
      union { ushort4 s4; __hip_bfloat162 h[2]; } st;
      st.h[0] = __float22bfloat162_rn(make_float2(o[g][db][0] * inv, o[g][db][1] * inv));
      st.h[1] = __float22bfloat162_rn(make_float2(o[g][db][2] * inv, o[g][db][3] * inv));
      *(ushort4*)(ob + ((size_t)(b * T_ + tg) * H_ + h) * DH + dh) = st.s4;
    }
  }
}

extern "C" void kernel_launch(void* const* d_in, const int* in_sizes, int n_in,
                              void* d_out, int out_size, void* d_ws, size_t ws_size,
                              hipStream_t stream) {
  const float* x  = (const float*)d_in[0];
  const float* k  = (const float*)d_in[1];
  const float* v  = (const float*)d_in[2];
  const float* wq = (const float*)d_in[3];
  const float* bq = (const float*)d_in[4];
  const float* wo = (const float*)d_in[5];
  const float* bo = (const float*)d_in[6];
  float* out = (float*)d_out;

  char* ws = (char*)d_ws;
  unsigned short* xb  = (unsigned short*)(ws + 0);
  unsigned short* wqb = (unsigned short*)(ws + 16777216);
  unsigned short* wob = (unsigned short*)(ws + 18874368);
  unsigned short* kbp = (unsigned short*)(ws + 20971520);
  unsigned short* vtp = (unsigned short*)(ws + 46137344);
  unsigned short* qsp = (unsigned short*)(ws + 71303168);
  unsigned short* obp = (unsigned short*)(ws + 88080384);

  prep_kernel<<<NB_CAST + NB_PK + NB_PVT, 256, 0, stream>>>(x, k, v, wq, wo, xb, wqb,
                                                            wob, kbp, vtp);
  gemm_bt<<<dim3(D_ / 128, B_ * T_ / 128), 256, 0, stream>>>(xb, wqb, bq, qsp, 0);
  attn_kernel<<<dim3(T_ / 128, B_ * H_), 256, 0, stream>>>(qsp, kbp, vtp, obp);
  gemm_bt<<<dim3(D_ / 128, B_ * T_ / 128), 256, 0, stream>>>(obp, wob, bo, out, 1);
}

// Round 6
// 300.819 us; speedup vs baseline: 1.4586x; 1.0445x over previous
//
#include <hip/hip_runtime.h>
#include <hip/hip_bf16.h>

typedef __attribute__((ext_vector_type(8))) short short8;
typedef __attribute__((ext_vector_type(4))) float floatx4;

#define B_ 8
#define T_ 1024
#define S_ 1500
#define SP 1536
#define D_ 1024
#define H_ 16
#define DH 64
// q-scale with log2(e) folded in: exp(x) = exp2(x * log2e)
#define SCALE2_ 0.1803368801111244f

__device__ __forceinline__ unsigned short f2bf(float f) {
  unsigned u = __float_as_uint(f);
  u += 0x7fffu + ((u >> 16) & 1u);
  return (unsigned short)(u >> 16);
}

__device__ __forceinline__ floatx4 mfma16(short8 a, short8 b, floatx4 c) {
  return __builtin_amdgcn_mfma_f32_16x16x32_bf16(a, b, c, 0, 0, 0);
}

// async global->LDS, 16B per lane. LDS dest = wave-uniform base + lane*16.
__device__ __forceinline__ void gload_lds16(const unsigned short* g, unsigned short* l) {
  __builtin_amdgcn_global_load_lds(
      (const __attribute__((address_space(1))) unsigned int*)g,
      (__attribute__((address_space(3))) unsigned int*)(unsigned long)(uintptr_t)l, 16, 0, 0);
}

// ---------------- fused prep: cast3 + pack_k + pack_vt in ONE kernel ---------
// block-range dispatch: [0,10240) cast3, [10240,22528) pack_k, [22528,25600) pack_vt
#define N1C (B_ * T_ * D_ / 4)
#define N2C (D_ * D_ / 4)
#define NB_CAST ((N1C + 2 * N2C) / 256)          // 10240
#define NB_PK (B_ * H_ * SP * 16 / 256)          // 12288
#define NB_PVT ((SP / 64) * B_ * H_)             // 3072
__global__ void prep_kernel(const float* __restrict__ x, const float* __restrict__ k,
                            const float* __restrict__ v, const float* __restrict__ wq,
                            const float* __restrict__ wo,
                            unsigned short* __restrict__ xb,
                            unsigned short* __restrict__ wqb,
                            unsigned short* __restrict__ wob,
                            unsigned short* __restrict__ kb,
                            unsigned short* __restrict__ vt) {
  __shared__ unsigned short tile[64][72];  // pack_vt only
  int bid = blockIdx.x;
  int t = threadIdx.x;
  if (bid < NB_CAST) {
    // ---- fused fp32 -> bf16 cast for x, wq, wo ----
    int i = bid * 256 + t;
    const float* src;
    unsigned short* dst;
    int j;
    if (i < N1C) {
      src = x; dst = xb; j = i;
    } else if (i < N1C + N2C) {
      src = wq; dst = wqb; j = i - N1C;
    } else {
      src = wo; dst = wob; j = i - N1C - N2C;
    }
    float4 val = ((const float4*)src)[j];
    ushort4 o;
    o.x = f2bf(val.x); o.y = f2bf(val.y); o.z = f2bf(val.z); o.w = f2bf(val.w);
    ((ushort4*)dst)[j] = o;
  } else if (bid < NB_CAST + NB_PK) {
    // ---- K [B,S,H,DH] f32 -> [B,H,SP,DH] bf16, ROW-PERMUTED ----
    int i = (bid - NB_CAST) * 256 + t;  // group of 4 dh
    int dh4 = (i & 15) * 4;
    int j = i >> 4;
    int s = j % SP;   // staged position
    int bh = j / SP;
    if (bh < B_ * H_) {
      int b = bh >> 4, h = bh & 15;
      int p = s & 31;
      int src = (s & ~31) + ((p >> 2) & 3) * 8 + ((p >> 4) & 1) * 4 + (p & 3);
      ushort4 o;
      if (src < S_) {
        float4 val = *(const float4*)(k + (((size_t)(b * S_ + src) * H_ + h) * DH) + dh4);
        o.x = f2bf(val.x); o.y = f2bf(val.y); o.z = f2bf(val.z); o.w = f2bf(val.w);
      } else {
        o = make_ushort4(0, 0, 0, 0);
      }
      *(ushort4*)(kb + ((size_t)bh * SP + s) * DH + dh4) = o;
    }
  } else {
    // ---- V [B,S,H,DH] f32 -> transposed [B,H,DH,SP] bf16 (plain order) ----
    int q = bid - NB_CAST - NB_PK;
    int st = q % (SP / 64), bh = q / (SP / 64);
    int b = bh >> 4, h = bh & 15;
    int s0 = st * 64;
    for (int i = t; i < 1024; i += 256) {
      int sl = i >> 4, dh4 = (i & 15) * 4;
      float4 val = make_float4(0.f, 0.f, 0.f, 0.f);
      if (s0 + sl < S_)
        val = *(const float4*)(v + ((size_t)((b * S_ + s0 + sl) * H_ + h)) * DH + dh4);
      tile[dh4 + 0][sl] = f2bf(val.x);
      tile[dh4 + 1][sl] = f2bf(val.y);
      tile[dh4 + 2][sl] = f2bf(val.z);
      tile[dh4 + 3][sl] = f2bf(val.w);
    }
    __syncthreads();
    for (int i = t; i < 1024; i += 256) {
      int d = i >> 4, s4 = (i & 15) * 4;
      ushort4 o;
      o.x = tile[d][s4]; o.y = tile[d][s4 + 1]; o.z = tile[d][s4 + 2]; o.w = tile[d][s4 + 3];
      *(ushort4*)(vt + ((size_t)bh * DH + d) * SP + s0 + s4) = o;
    }
  }
}

// ---------------- bf16 GEMM  C[m,n] = sum_k A[m,k]*B[n,k]  (+bias epilogues) -----
// R6: T3-minimum 2-phase pipeline (catalog recipe, 622-682 TF proven; m248:
// ~660 TF at K=1024). R5 showed halving the drain COUNT was neutral -> the
// serial-per-iter drain (stage; vmcnt(0); barrier; compute) was the bound.
// Now: double-buffered LDS; STAGE(tile n+1) issued BEFORE compute(tile n);
// ONE __syncthreads per iter whose compiler-emitted vmcnt(0) waits on loads
// that had the whole ds_read+MFMA phase to land -> drain off critical path.
// XCD-chunked remap: 512 blocks, XCD gets 8 m-tiles x all 8 n-tiles ->
// A+B footprint 4MB/XCD ~= L2 (was: all 16.8MB of A streamed per XCD).
// LDS 2x32KB = 64KB -> 2 blocks/CU, matching the 512-block grid exactly.
// XOR swizzle: physical 16B-slot c at row r holds global chunk c ^ (r&7);
// fragment ds_read_b128 lands 2 lanes/bank (free, m136). setprio omitted
// (T5 proven null at 2-phase, m230b).
// epi=0: qs output bf16, (val+bias)*SCALE2 (log2e folded), permuted to [B,H,T,DH]
// epi=1: fp32 output, val+bias, row-major [M,1024]
#define BK2 64
__global__ __launch_bounds__(256, 2) void gemm_bt(const unsigned short* __restrict__ A,
                                                  const unsigned short* __restrict__ Bm,
                                                  const float* __restrict__ bias,
                                                  void* __restrict__ outp, int epi) {
  __shared__ unsigned short As[2][128 * BK2];
  __shared__ unsigned short Bs[2][128 * BK2];
  const int K = 1024;
  const int NKT = K / BK2;  // 16
  int t = threadIdx.x;
  // XCD-chunked remap: dispatch id p runs on XCD p%8; give each XCD a
  // contiguous rid-range = 8 m-tiles x 8 n-tiles (bijective, 512%8==0).
  int p = blockIdx.x + (blockIdx.y << 3);
  int rid = (p & 7) * 64 + (p >> 3);
  int m0 = (rid >> 3) * 128, n0 = (rid & 7) * 128;
  int w = t >> 6, lane = t & 63, quad = lane >> 4, l16 = lane & 15;
  int mw = (w & 1) * 64, nw = (w >> 1) * 64;

  // staging: per wave-instr 8 rows x 8 slots; lane -> (rloc = lane>>3, c = lane&7).
  // slot c at row r must hold global chunk c ^ (r&7); staged row bases are
  // 8-aligned so r&7 == rloc.
  int rloc = lane >> 3, cslot = lane & 7;
  int gch = cslot ^ rloc;
  const unsigned short* paw = A + (size_t)(m0 + w * 8 + rloc) * K + gch * 8;
  const unsigned short* pbw = Bm + (size_t)(n0 + w * 8 + rloc) * K + gch * 8;
  int lofs = (w * 8) * BK2;  // + p2*32*BK2

  floatx4 acc[4][4];
#pragma unroll
  for (int i = 0; i < 4; i++)
#pragma unroll
    for (int j = 0; j < 4; j++) {
      floatx4 z = {0.f, 0.f, 0.f, 0.f};
      acc[i][j] = z;
    }

  int arow = mw + l16;  // + mi*16
  int brow = nw + l16;  // + ni*16
  int sl7 = l16 & 7;    // r&7 for all fragment rows (16-multiples preserve it)

  // prologue: stage tile 0 into buf 0, wait (auto vmcnt(0)+barrier)
#pragma unroll
  for (int p2 = 0; p2 < 4; p2++) {
    gload_lds16(paw + (size_t)(p2 * 32) * K, &As[0][lofs + p2 * 32 * BK2]);
    gload_lds16(pbw + (size_t)(p2 * 32) * K, &Bs[0][lofs + p2 * 32 * BK2]);
  }
  __syncthreads();

  int cur = 0;
  for (int kt = 0; kt < NKT; kt++) {
    if (kt + 1 < NKT) {  // issue next tile's loads FIRST (drain overlaps compute)
#pragma unroll
      for (int p2 = 0; p2 < 4; p2++) {
        gload_lds16(paw + (size_t)(p2 * 32) * K + (kt + 1) * BK2,
                    &As[cur ^ 1][lofs + p2 * 32 * BK2]);
        gload_lds16(pbw + (size_t)(p2 * 32) * K + (kt + 1) * BK2,
                    &Bs[cur ^ 1][lofs + p2 * 32 * BK2]);
      }
    }
#pragma unroll
    for (int hf = 0; hf < 2; hf++) {
      int slot = ((hf << 2) | quad) ^ sl7;
      short8 af[4], bf[4];
#pragma unroll
      for (int mi = 0; mi < 4; mi++)
        af[mi] = *(const short8*)&As[cur][(arow + mi * 16) * BK2 + slot * 8];
#pragma unroll
      for (int ni = 0; ni < 4; ni++)
        bf[ni] = *(const short8*)&Bs[cur][(brow + ni * 16) * BK2 + slot * 8];
#pragma unroll
      for (int mi = 0; mi < 4; mi++)
#pragma unroll
        for (int ni = 0; ni < 4; ni++)
          acc[mi][ni] = mfma16(af[mi], bf[ni], acc[mi][ni]);
    }
    __syncthreads();  // drains vmcnt (next tile staged) + all reads of cur done
    cur ^= 1;
  }

#pragma unroll
  for (int mi = 0; mi < 4; mi++)
#pragma unroll
    for (int ni = 0; ni < 4; ni++) {
      int row = m0 + mw + mi * 16 + quad * 4;
      int col = n0 + nw + ni * 16 + l16;
      float bcol = bias[col];
#pragma unroll
      for (int r = 0; r < 4; r++) {
        float val = acc[mi][ni][r] + bcol;
        int rr = row + r;
        if (epi == 0) {
          int b = rr >> 10, tt = rr & 1023, h = col >> 6, dh = col & 63;
          ((unsigned short*)outp)[(((size_t)(b * 16 + h) * 1024) + tt) * 64 + dh] =
              f2bf(val * SCALE2_);
        } else {
          ((float*)outp)[(size_t)rr * 1024 + col] = val;
        }
      }
    }
}

// ---------------- fused flash attention, Sc^T scheme, 4-wave blocks ----------
// (unchanged from R4: 125 -> 104us, prediction-validated structure)
//  * 4-wave blocks, wave owns 32 t-cols; 1024 blocks = 4 barrier domains/CU.
//  * double-buffered K/V LDS: ONE barrier per 64-s tile.
//  * staging loads issued TWO tiles ahead.
//  * defer-max (T13, THR=8 base-2).
// Scores transposed: C col = t (lane), row = staged s. K staged row-permuted so
// P fragments re-pack in-lane as PV B-operand. Softmax in base-2 domain.
#define NT (SP / 64)
__global__ __launch_bounds__(256, 4) void attn_kernel(
    const unsigned short* __restrict__ qs, const unsigned short* __restrict__ kb,
    const unsigned short* __restrict__ vt, unsigned short* __restrict__ ob) {
  __shared__ unsigned short Ks[2][64 * 72];   // [buf][staged s][dh] padded
  __shared__ unsigned short Vs[2][64 * 72];   // [buf][dh][s] padded (plain order)
  // XCD-chunked remap: linear id p runs on XCD p%8; bh = p&127 puts the 8
  // t-tiles of each bh on one XCD (p = bh, bh+128, ... same mod 8).
  int p = blockIdx.x + (blockIdx.y << 3);
  int ttile = p >> 7, bh = p & 127;
  int b = bh >> 4, h = bh & 15;
  int t = threadIdx.x, w = t >> 6, lane = t & 63, quad = lane >> 4, l16 = lane & 15;

  // Q as B-operand: two t-groups at w*32 and w*32+16; n = l16, k(dh) = quad*8+j
  const unsigned short* qp =
      qs + ((size_t)bh * T_ + ttile * 128 + w * 32 + l16) * DH + quad * 8;
  short8 qa[2][2];
  qa[0][0] = *(const short8*)(qp);
  qa[0][1] = *(const short8*)(qp + 32);
  qa[1][0] = *(const short8*)(qp + 16 * DH);
  qa[1][1] = *(const short8*)(qp + 16 * DH + 32);

  const unsigned short* kbase = kb + (size_t)bh * SP * DH;
  const unsigned short* vbase = vt + (size_t)bh * DH * SP;

  // staging roles: 256 threads, 1024 int4 per tile -> 4 int4/thread (2 K + 2 V)
  int sr = t >> 3, c8 = (t & 7) * 8;
  const unsigned short* ksp0 = kbase + (size_t)sr * DH + c8;
  const unsigned short* ksp1 = kbase + (size_t)(sr + 32) * DH + c8;
  const unsigned short* vsp0 = vbase + (size_t)sr * SP + c8;
  const unsigned short* vsp1 = vbase + (size_t)(sr + 32) * SP + c8;
  int klo0 = sr * 72 + c8, klo1 = (sr + 32) * 72 + c8;
  int vlo0 = sr * 72 + c8, vlo1 = (sr + 32) * 72 + c8;

  floatx4 o[2][4];  // O^T acc per t-group: col=t(l16), row = db*16 + quad*4 + r
#pragma unroll
  for (int g = 0; g < 2; g++)
#pragma unroll
    for (int i = 0; i < 4; i++) {
      floatx4 z = {0.f, 0.f, 0.f, 0.f};
      o[g][i] = z;
    }
  float mrow[2] = {-1e30f, -1e30f};
  float lrow[2] = {0.f, 0.f};

  // prologue: tile0 -> regs -> buf0; issue tile1 loads
  int4 rk0 = *(const int4*)(ksp0);
  int4 rk1 = *(const int4*)(ksp1);
  int4 rv0 = *(const int4*)(vsp0);
  int4 rv1 = *(const int4*)(vsp1);
  *(int4*)&Ks[0][klo0] = rk0;
  *(int4*)&Ks[0][klo1] = rk1;
  *(int4*)&Vs[0][vlo0] = rv0;
  *(int4*)&Vs[0][vlo1] = rv1;
  rk0 = *(const int4*)(ksp0 + (size_t)64 * DH);
  rk1 = *(const int4*)(ksp1 + (size_t)64 * DH);
  rv0 = *(const int4*)(vsp0 + 64);
  rv1 = *(const int4*)(vsp1 + 64);

  for (int n = 0; n < NT; n++) {
    int s0 = n * 64;
    int cur = n & 1;
    __syncthreads();  // buf[cur] writes visible; buf[cur^1] reads (tile n-1) done
    if (n + 1 < NT) {  // write tile n+1 (regs) into the other buffer
      *(int4*)&Ks[cur ^ 1][klo0] = rk0;
      *(int4*)&Ks[cur ^ 1][klo1] = rk1;
      *(int4*)&Vs[cur ^ 1][vlo0] = rv0;
      *(int4*)&Vs[cur ^ 1][vlo1] = rv1;
    }
    if (n + 2 < NT) {  // issue loads for tile n+2 (consumed next iteration)
      size_t so = (size_t)(s0 + 128);
      rk0 = *(const int4*)(ksp0 + so * DH);
      rk1 = *(const int4*)(ksp1 + so * DH);
      rv0 = *(const int4*)(vsp0 + so);
      rv1 = *(const int4*)(vsp1 + so);
    }

    // Sc^T: per lane, per t-group, 16 staged-s values of its own t-row.
    // Each K fragment read feeds BOTH t-groups' mfmas.
    floatx4 sc[2][4];
#pragma unroll
    for (int nb = 0; nb < 4; nb++) {
      short8 k0 = *(const short8*)&Ks[cur][(nb * 16 + l16) * 72 + quad * 8];
      short8 k1 = *(const short8*)&Ks[cur][(nb * 16 + l16) * 72 + 32 + quad * 8];
      floatx4 a = {0.f, 0.f, 0.f, 0.f};
      a = mfma16(k0, qa[0][0], a);
      a = mfma16(k1, qa[0][1], a);
      sc[0][nb] = a;
      floatx4 a2 = {0.f, 0.f, 0.f, 0.f};
      a2 = mfma16(k0, qa[1][0], a2);
      a2 = mfma16(k1, qa[1][1], a2);
      sc[1][nb] = a2;
    }
    if (s0 + 64 > S_) {  // mask padded actual-s (last tile only)
#pragma unroll
      for (int nb = 0; nb < 4; nb++)
#pragma unroll
        for (int r = 0; r < 4; r++) {
          int s_act = s0 + (nb >> 1) * 32 + quad * 8 + (nb & 1) * 4 + r;
          if (s_act >= S_) { sc[0][nb][r] = -1e30f; sc[1][nb][r] = -1e30f; }
        }
    }

    // online softmax (base 2) per t-group, defer-max: only rescale when the
    // tile max exceeds the running max by >8 (then P <= 2^8, fp32-safe)
#pragma unroll
    for (int g = 0; g < 2; g++) {
      float mx = -1e30f;
#pragma unroll
      for (int nb = 0; nb < 4; nb++) {
        float a0m = fmaxf(sc[g][nb][0], sc[g][nb][1]);
        float a1m = fmaxf(sc[g][nb][2], sc[g][nb][3]);
        mx = fmaxf(mx, fmaxf(a0m, a1m));
      }
      mx = fmaxf(mx, __shfl_xor(mx, 16));
      mx = fmaxf(mx, __shfl_xor(mx, 32));
      if (__any(mx > mrow[g] + 8.0f)) {
        float mnew = fmaxf(mrow[g], mx);
        float alpha = exp2f(mrow[g] - mnew);
        mrow[g] = mnew;
        lrow[g] *= alpha;
#pragma unroll
        for (int db = 0; db < 4; db++) {
          o[g][db][0] *= alpha; o[g][db][1] *= alpha;
          o[g][db][2] *= alpha; o[g][db][3] *= alpha;
        }
      }
      float m = mrow[g];
      float rs = 0.f;
#pragma unroll
      for (int nb = 0; nb < 4; nb++)
#pragma unroll
        for (int r = 0; r < 4; r++) {
          float p2 = exp2f(sc[g][nb][r] - m);
          sc[g][nb][r] = p2;
          rs += p2;
        }
      rs += __shfl_xor(rs, 16);
      rs += __shfl_xor(rs, 32);
      lrow[g] += rs;
    }

    // PV: O^T[d][t] += V^T(A) * P(B). chunk c covers staged s = c*32..c*32+31.
    // Each V fragment read feeds BOTH t-groups' mfmas.
#pragma unroll
    for (int c = 0; c < 2; c++) {
      union { short8 v; __hip_bfloat162 h[4]; } pk0, pk1;
      pk0.h[0] = __float22bfloat162_rn(make_float2(sc[0][2 * c][0], sc[0][2 * c][1]));
      pk0.h[1] = __float22bfloat162_rn(make_float2(sc[0][2 * c][2], sc[0][2 * c][3]));
      pk0.h[2] = __float22bfloat162_rn(make_float2(sc[0][2 * c + 1][0], sc[0][2 * c + 1][1]));
      pk0.h[3] = __float22bfloat162_rn(make_float2(sc[0][2 * c + 1][2], sc[0][2 * c + 1][3]));
      pk1.h[0] = __float22bfloat162_rn(make_float2(sc[1][2 * c][0], sc[1][2 * c][1]));
      pk1.h[1] = __float22bfloat162_rn(make_float2(sc[1][2 * c][2], sc[1][2 * c][3]));
      pk1.h[2] = __float22bfloat162_rn(make_float2(sc[1][2 * c + 1][0], sc[1][2 * c + 1][1]));
      pk1.h[3] = __float22bfloat162_rn(make_float2(sc[1][2 * c + 1][2], sc[1][2 * c + 1][3]));
#pragma unroll
      for (int db = 0; db < 4; db++) {
        short8 vf = *(const short8*)&Vs[cur][(db * 16 + l16) * 72 + c * 32 + quad * 8];
        o[0][db] = mfma16(vf, pk0.v, o[0][db]);
        o[1][db] = mfma16(vf, pk1.v, o[1][db]);
      }
    }
  }

#pragma unroll
  for (int g = 0; g < 2; g++) {
    float inv = 1.0f / lrow[g];
    int tg = ttile * 128 + w * 32 + g * 16 + l16;
#pragma unroll
    for (int db = 0; db < 4; db++) {
      int dh = db * 16 + quad * 4;
      union { ushort4 s4; __hip_bfloat162 h[2]; } st;
      st.h[0] = __float22bfloat162_rn(make_float2(o[g][db][0] * inv, o[g][db][1] * inv));
      st.h[1] = __float22bfloat162_rn(make_float2(o[g][db][2] * inv, o[g][db][3] * inv));
      *(ushort4*)(ob + ((size_t)(b * T_ + tg) * H_ + h) * DH + dh) = st.s4;
    }
  }
}

extern "C" void kernel_launch(void* const* d_in, const int* in_sizes, int n_in,
                              void* d_out, int out_size, void* d_ws, size_t ws_size,
                              hipStream_t stream) {
  const float* x  = (const float*)d_in[0];
  const float* k  = (const float*)d_in[1];
  const float* v  = (const float*)d_in[2];
  const float* wq = (const float*)d_in[3];
  const float* bq = (const float*)d_in[4];
  const float* wo = (const float*)d_in[5];
  const float* bo = (const float*)d_in[6];
  float* out = (float*)d_out;

  char* ws = (char*)d_ws;
  unsigned short* xb  = (unsigned short*)(ws + 0);
  unsigned short* wqb = (unsigned short*)(ws + 16777216);
  unsigned short* wob = (unsigned short*)(ws + 18874368);
  unsigned short* kbp = (unsigned short*)(ws + 20971520);
  unsigned short* vtp = (unsigned short*)(ws + 46137344);
  unsigned short* qsp = (unsigned short*)(ws + 71303168);
  unsigned short* obp = (unsigned short*)(ws + 88080384);

  prep_kernel<<<NB_CAST + NB_PK + NB_PVT, 256, 0, stream>>>(x, k, v, wq, wo, xb, wqb,
                                                            wob, kbp, vtp);
  gemm_bt<<<dim3(D_ / 128, B_ * T_ / 128), 256, 0, stream>>>(xb, wqb, bq, qsp, 0);
  attn_kernel<<<dim3(T_ / 128, B_ * H_), 256, 0, stream>>>(qsp, kbp, vtp, obp);
  gemm_bt<<<dim3(D_ / 128, B_ * T_ / 128), 256, 0, stream>>>(obp, wob, bo, out, 1);
}